// Round 1
// baseline (400.969 us; speedup 1.0000x reference)
//
#include <hip/hip_runtime.h>

// ---------------------------------------------------------------------------
// SelfAttentionRPR: B=8, T=1024, D=128, K=64, DEPTH=1, all fp32.
//
// out = relu( attn( tanh-proj(relu(x@W0+b0)) ) @ W1 + b1 )
// RPR-key term folded into 129 extra K-rows (pe_key -> qpe logits stored in
// score cols 1024..1152); RPR-value term folded into bucket weights w[129]
// stored back into the same cols, consumed as 129 extra V-rows (pe_value).
// ---------------------------------------------------------------------------

#define TT 1024          // sequence length
#define DD 128           // head dim
#define NB 8             // batch
#define NEXT 1153        // 1024 + 129 extended columns

#define SJ  1156         // score-row stride (floats), 16B-aligned, >= NEXT
#define KVJ 133          // K/V tile stride: bank (5j+d)%32 -> conflict-free
#define QJ  132          // Q tile stride (16B-aligned for float4 reads)

// ---------------------------------------------------------------------------
// GEMM: Y[8192,128] = act(X[8192,128] @ W[128,128] + b).  ACT: 0=relu 1=tanh
// 32 rows/block, 256 threads (4 waves; wave wv owns rows 8wv..8wv+7).
// W columns live in registers (wA/wB, 32 each per 32-k chunk); LDS holds X
// only, read as broadcast float4 -> compute-bound inner loop.
// ---------------------------------------------------------------------------
template<int ACT>
__global__ __launch_bounds__(256) void gemm_act(const float* __restrict__ X,
        const float* __restrict__ W, const float* __restrict__ Bv,
        float* __restrict__ Y) {
    __shared__ float xs[32 * QJ];
    const int t  = threadIdx.x;
    const int r0 = blockIdx.x << 5;
    const int wv = t >> 6;
    const int tx = t & 63;

    // stage X 32x128 (float4, coalesced)
    for (int idx = t; idx < 32 * 32; idx += 256) {
        int r = idx >> 5, c4 = (idx & 31) << 2;
        *(float4*)&xs[r * QJ + c4] = *(const float4*)&X[(size_t)(r0 + r) * DD + c4];
    }
    __syncthreads();

    float acc[8][2];
    #pragma unroll
    for (int r = 0; r < 8; r++) { acc[r][0] = 0.f; acc[r][1] = 0.f; }

    for (int k0 = 0; k0 < DD; k0 += 32) {
        float wA[32], wB[32];
        #pragma unroll
        for (int kk = 0; kk < 32; kk++) {
            wA[kk] = W[(size_t)(k0 + kk) * DD + tx];
            wB[kk] = W[(size_t)(k0 + kk) * DD + tx + 64];
        }
        #pragma unroll
        for (int kq = 0; kq < 8; kq++) {
            #pragma unroll
            for (int r = 0; r < 8; r++) {
                float4 xq = *(const float4*)&xs[(8 * wv + r) * QJ + k0 + 4 * kq];
                float xa[4] = {xq.x, xq.y, xq.z, xq.w};
                #pragma unroll
                for (int dd = 0; dd < 4; dd++) {
                    acc[r][0] += xa[dd] * wA[4 * kq + dd];
                    acc[r][1] += xa[dd] * wB[4 * kq + dd];
                }
            }
        }
    }

    const float ba = Bv[tx], bb = Bv[tx + 64];
    #pragma unroll
    for (int r = 0; r < 8; r++) {
        size_t row = (size_t)(r0 + 8 * wv + r) * DD;
        float v0 = acc[r][0] + ba;
        float v1 = acc[r][1] + bb;
        if (ACT == 0) { v0 = v0 > 0.f ? v0 : 0.f; v1 = v1 > 0.f ? v1 : 0.f; }
        else          { v0 = tanhf(v0);           v1 = tanhf(v1); }
        Y[row + tx]      = v0;
        Y[row + tx + 64] = v1;
    }
}

// ---------------------------------------------------------------------------
// Fused attention: one block = (batch b, 16 query rows).
// Phase 1 (QK): tiles over extended K' = [pe_key(129); K(1024)], scores into
//               S[16][SJ] (qpe at cols 1024+m).  Wave wv computes rows
//               4wv..4wv+3 -> softmax needs no inter-wave barrier.
// Phase 2: per-row softmax (16 lanes/row), logits = qk + qpe[id], p=exp(s-m)
//          kept UNNORMALIZED; bucket weights w[129] written into cols 1024+m;
//          row denominators into LR.
// Phase 3 (PV): tiles over extended V' = [V(1024); pe_value(129)], lane owns
//               d in {tx, tx+64}; final divide by LR, write C.
// ---------------------------------------------------------------------------
__global__ __launch_bounds__(256) void attn_kernel(
        const float* __restrict__ Qm, const float* __restrict__ Km,
        const float* __restrict__ Vm, const float* __restrict__ PEK,
        const float* __restrict__ PEV, float* __restrict__ Cm) {
    extern __shared__ float sm[];
    float* S  = sm;                  // [16][SJ]
    float* KV = S + 16 * SJ;         // [128][KVJ]
    float* QL = KV + 128 * KVJ;      // [16][QJ]
    float* LR = QL + 16 * QJ;        // [16]

    const int t  = threadIdx.x;
    const int b  = blockIdx.x >> 6;
    const int i0 = (blockIdx.x & 63) << 4;
    const int wv = t >> 6;
    const int tx = t & 63;

    // stage Q tile (16 x 128)
    {
        const float* src = Qm + ((size_t)b * TT + i0) * DD;
        for (int idx = t; idx < 16 * DD; idx += 256) {
            int i = idx >> 7, d = idx & 127;
            QL[i * QJ + d] = src[i * DD + d];
        }
    }

    // ---------------- Phase 1: extended QK ----------------
    for (int tile = 0; tile < 10; tile++) {
        int nr, destbase;
        const float* src;
        if (tile < 2) {                       // pe_key tiles (129 rows total)
            nr = (tile == 0) ? 128 : 1;
            src = PEK + (size_t)tile * 128 * DD;
            destbase = 1024 + tile * 128;
        } else {                              // K tiles
            nr = 128;
            src = Km + ((size_t)b * TT + (size_t)(tile - 2) * 128) * DD;
            destbase = (tile - 2) * 128;
        }
        __syncthreads();                      // prev compute done with KV
        for (int idx = t; idx < (nr << 7); idx += 256) {
            int j = idx >> 7, d = idx & 127;
            KV[j * KVJ + d] = src[(size_t)j * DD + d];
        }
        __syncthreads();

        const bool okA = tx < nr, okB = (tx + 64) < nr;
        float aA0 = 0, aA1 = 0, aA2 = 0, aA3 = 0;
        float aB0 = 0, aB1 = 0, aB2 = 0, aB3 = 0;
        if (okA | okB) {
            const float* q0 = QL + (4 * wv + 0) * QJ;
            const float* q1 = QL + (4 * wv + 1) * QJ;
            const float* q2 = QL + (4 * wv + 2) * QJ;
            const float* q3 = QL + (4 * wv + 3) * QJ;
            const float* ka = KV + tx * KVJ;
            const float* kb = KV + (tx + 64) * KVJ;   // row <= 127, in-bounds
            #pragma unroll 8
            for (int d4 = 0; d4 < 32; d4++) {
                float4 x0 = *(const float4*)(q0 + 4 * d4);
                float4 x1 = *(const float4*)(q1 + 4 * d4);
                float4 x2 = *(const float4*)(q2 + 4 * d4);
                float4 x3 = *(const float4*)(q3 + 4 * d4);
                float e0[4] = {x0.x, x0.y, x0.z, x0.w};
                float e1[4] = {x1.x, x1.y, x1.z, x1.w};
                float e2[4] = {x2.x, x2.y, x2.z, x2.w};
                float e3[4] = {x3.x, x3.y, x3.z, x3.w};
                #pragma unroll
                for (int dd = 0; dd < 4; dd++) {
                    float fa = ka[4 * d4 + dd];
                    float fb = kb[4 * d4 + dd];
                    aA0 += e0[dd] * fa; aA1 += e1[dd] * fa;
                    aA2 += e2[dd] * fa; aA3 += e3[dd] * fa;
                    aB0 += e0[dd] * fb; aB1 += e1[dd] * fb;
                    aB2 += e2[dd] * fb; aB3 += e3[dd] * fb;
                }
            }
        }
        if (okA) {
            S[(4 * wv + 0) * SJ + destbase + tx] = aA0;
            S[(4 * wv + 1) * SJ + destbase + tx] = aA1;
            S[(4 * wv + 2) * SJ + destbase + tx] = aA2;
            S[(4 * wv + 3) * SJ + destbase + tx] = aA3;
        }
        if (okB) {
            S[(4 * wv + 0) * SJ + destbase + tx + 64] = aB0;
            S[(4 * wv + 1) * SJ + destbase + tx + 64] = aB1;
            S[(4 * wv + 2) * SJ + destbase + tx + 64] = aB2;
            S[(4 * wv + 3) * SJ + destbase + tx + 64] = aB3;
        }
    }

    // ---------------- Phase 2: softmax + buckets (wave-local rows) --------
    {
        const int row = t >> 4;        // == 4*wv + (t>>4 & 3): same wave's rows
        const int l16 = t & 15;
        const int ig  = i0 + row;
        float* srow = S + row * SJ;

        float lmax = -3.0e38f;
        for (int j = l16; j < TT; j += 16) {
            int idd = 64 + j - ig;
            idd = idd < 0 ? 0 : (idd > 128 ? 128 : idd);
            float logit = srow[j] + srow[1024 + idd];
            srow[j] = logit;
            lmax = fmaxf(lmax, logit);
        }
        #pragma unroll
        for (int off = 8; off; off >>= 1) lmax = fmaxf(lmax, __shfl_xor(lmax, off, 64));

        float lsum = 0.f, s0 = 0.f, s1 = 0.f;
        for (int j = l16; j < TT; j += 16) {
            int idd = 64 + j - ig;
            idd = idd < 0 ? 0 : (idd > 128 ? 128 : idd);
            float p = __expf(srow[j] - lmax);
            srow[j] = p;                       // unnormalized
            lsum += p;
            s0 += (idd == 0)   ? p : 0.f;
            s1 += (idd == 128) ? p : 0.f;
        }
        #pragma unroll
        for (int off = 8; off; off >>= 1) {
            lsum += __shfl_xor(lsum, off, 64);
            s0   += __shfl_xor(s0,   off, 64);
            s1   += __shfl_xor(s1,   off, 64);
        }
        if (l16 == 0) LR[row] = lsum;

        // bucket weights -> cols 1024+m (qpe fully consumed above)
        for (int m = l16; m < 129; m += 16) {
            float wval;
            if (m == 0)        wval = s0;
            else if (m == 128) wval = s1;
            else {
                int jm = ig + m - 64;
                wval = (jm >= 0 && jm < TT) ? srow[jm] : 0.f;
            }
            srow[1024 + m] = wval;
        }
    }

    // ---------------- Phase 3: extended PV ----------------
    float c00 = 0, c01 = 0, c02 = 0, c03 = 0;   // d = tx
    float c10 = 0, c11 = 0, c12 = 0, c13 = 0;   // d = tx+64
    for (int tile = 0; tile < 10; tile++) {
        int r0 = tile << 7;
        int nr = (r0 + 128 <= NEXT) ? 128 : (NEXT - r0);
        const float* src = (r0 < 1024)
                ? (Vm + ((size_t)b * TT + r0) * DD)
                : (PEV + (size_t)(r0 - 1024) * DD);
        __syncthreads();                      // all waves done with KV (and QK/softmax)
        for (int idx = t; idx < (nr << 7); idx += 256) {
            int j = idx >> 7, d = idx & 127;
            KV[j * KVJ + d] = src[(size_t)j * DD + d];
        }
        __syncthreads();

        const float* p0 = S + (4 * wv + 0) * SJ + r0;
        const float* p1 = S + (4 * wv + 1) * SJ + r0;
        const float* p2 = S + (4 * wv + 2) * SJ + r0;
        const float* p3 = S + (4 * wv + 3) * SJ + r0;
        const int nub = (nr + 3) >> 2;
        for (int ub = 0; ub < nub; ub++) {
            float4 f0 = *(const float4*)(p0 + 4 * ub);
            float4 f1 = *(const float4*)(p1 + 4 * ub);
            float4 f2 = *(const float4*)(p2 + 4 * ub);
            float4 f3 = *(const float4*)(p3 + 4 * ub);
            float g0[4] = {f0.x, f0.y, f0.z, f0.w};
            float g1[4] = {f1.x, f1.y, f1.z, f1.w};
            float g2[4] = {f2.x, f2.y, f2.z, f2.w};
            float g3[4] = {f3.x, f3.y, f3.z, f3.w};
            #pragma unroll
            for (int w = 0; w < 4; w++) {
                int jj = 4 * ub + w;
                if (jj < nr) {
                    const float* vr = KV + jj * KVJ;
                    float va = vr[tx], vb = vr[tx + 64];
                    c00 += g0[w] * va; c01 += g1[w] * va;
                    c02 += g2[w] * va; c03 += g3[w] * va;
                    c10 += g0[w] * vb; c11 += g1[w] * vb;
                    c12 += g2[w] * vb; c13 += g3[w] * vb;
                }
            }
        }
    }

    // finalize: divide by denominator, write C
    {
        float* dst = Cm + ((size_t)b * TT + i0 + 4 * wv) * DD;
        float r0v = 1.f / LR[4 * wv + 0];
        float r1v = 1.f / LR[4 * wv + 1];
        float r2v = 1.f / LR[4 * wv + 2];
        float r3v = 1.f / LR[4 * wv + 3];
        dst[tx]            = c00 * r0v;  dst[tx + 64]            = c10 * r0v;
        dst[DD + tx]       = c01 * r1v;  dst[DD + tx + 64]       = c11 * r1v;
        dst[2 * DD + tx]   = c02 * r2v;  dst[2 * DD + tx + 64]   = c12 * r2v;
        dst[3 * DD + tx]   = c03 * r3v;  dst[3 * DD + tx + 64]   = c13 * r3v;
    }
}

// ---------------------------------------------------------------------------

extern "C" void kernel_launch(void* const* d_in, const int* in_sizes, int n_in,
                              void* d_out, int out_size, void* d_ws, size_t ws_size,
                              hipStream_t stream) {
    const float* x   = (const float*)d_in[0];
    const float* W0  = (const float*)d_in[1];
    const float* b0  = (const float*)d_in[2];
    const float* Wq  = (const float*)d_in[3];
    const float* bq  = (const float*)d_in[4];
    const float* Wk  = (const float*)d_in[5];
    const float* bk  = (const float*)d_in[6];
    const float* Wv  = (const float*)d_in[7];
    const float* bv  = (const float*)d_in[8];
    const float* W1  = (const float*)d_in[9];
    const float* b1  = (const float*)d_in[10];
    const float* pek = (const float*)d_in[11];
    const float* pev = (const float*)d_in[12];
    float* out = (float*)d_out;

    const size_t NTD = (size_t)NB * TT * DD;   // 1,048,576 floats = 4 MB
    float* hs = (float*)d_ws;
    float* q  = hs + NTD;
    float* k  = q  + NTD;
    float* v  = k  + NTD;
    float* c  = v  + NTD;

    const int SMEM_ATTN = (16 * SJ + 128 * KVJ + 16 * QJ + 16) * 4;  // 150,592 B
    hipFuncSetAttribute(reinterpret_cast<const void*>(attn_kernel),
                        hipFuncAttributeMaxDynamicSharedMemorySize, SMEM_ATTN);

    hipLaunchKernelGGL((gemm_act<0>), dim3(256), dim3(256), 0, stream, x,  W0, b0, hs);
    hipLaunchKernelGGL((gemm_act<1>), dim3(256), dim3(256), 0, stream, hs, Wq, bq, q);
    hipLaunchKernelGGL((gemm_act<1>), dim3(256), dim3(256), 0, stream, hs, Wk, bk, k);
    hipLaunchKernelGGL((gemm_act<1>), dim3(256), dim3(256), 0, stream, hs, Wv, bv, v);
    hipLaunchKernelGGL(attn_kernel, dim3(512), dim3(256), SMEM_ATTN, stream,
                       q, k, v, pek, pev, c);
    hipLaunchKernelGGL((gemm_act<0>), dim3(256), dim3(256), 0, stream, c, W1, b1, out);
}

// Round 2
// 145.353 us; speedup vs baseline: 2.7586x; 2.7586x over previous
//
#include <hip/hip_runtime.h>

// ---------------------------------------------------------------------------
// SelfAttentionRPR: B=8, T=1024, D=128, K=64, DEPTH=1, fp32 in/out.
// Attention runs on bf16 MFMA (16x16x32); GEMMs stay fp32 vector this round.
//
// RPR-key folded into 128 extra K-rows (pe_key -> qpe logits at S cols
// 1024..1151) + scalar qpe[128]; RPR-value folded into bucket weights w[m]
// written back into the same cols and consumed as 128 extra V-rows
// (pe_value), + scalar w[128]*pe_value[128] in the epilogue.
//
// K and V^T are pre-converted to bf16 "LDS image" tiles (32 KB each) with the
// XOR swizzle  byte ^= ((row&7)<<4)  baked into the global layout, so the
// attention kernel stages them with plain coalesced 16B copies and reads MFMA
// fragments with conflict-optimal ds_read_b128.
// ---------------------------------------------------------------------------

#define TT 1024
#define DD 128
#define NB 8
#define SJ 1164          // S row stride (floats): 1164%32=12 -> uniform banks
#define QJ 132           // gemm X-tile stride

typedef __attribute__((ext_vector_type(8))) short bf16x8;   // 8 bf16 (4 VGPR)
typedef __attribute__((ext_vector_type(8))) unsigned short u16x8;
typedef __attribute__((ext_vector_type(4))) float f32x4;

static __device__ inline unsigned short f2bf(float f) {     // RNE float->bf16
    unsigned u = __float_as_uint(f);
    return (unsigned short)((u + 0x7fffu + ((u >> 16) & 1u)) >> 16);
}
static __device__ inline unsigned packbf(float a, float b) {
    return (unsigned)f2bf(a) | ((unsigned)f2bf(b) << 16);
}

// ---------------------------------------------------------------------------
// GEMM: Y[8192,128] = act(X @ W + b).  ACT: 0=relu 1=tanh.  (unchanged, R0)
// ---------------------------------------------------------------------------
template<int ACT>
__global__ __launch_bounds__(256) void gemm_act(const float* __restrict__ X,
        const float* __restrict__ W, const float* __restrict__ Bv,
        float* __restrict__ Y) {
    __shared__ float xs[32 * QJ];
    const int t  = threadIdx.x;
    const int r0 = blockIdx.x << 5;
    const int wv = t >> 6;
    const int tx = t & 63;

    for (int idx = t; idx < 32 * 32; idx += 256) {
        int r = idx >> 5, c4 = (idx & 31) << 2;
        *(float4*)&xs[r * QJ + c4] = *(const float4*)&X[(size_t)(r0 + r) * DD + c4];
    }
    __syncthreads();

    float acc[8][2];
    #pragma unroll
    for (int r = 0; r < 8; r++) { acc[r][0] = 0.f; acc[r][1] = 0.f; }

    for (int k0 = 0; k0 < DD; k0 += 32) {
        float wA[32], wB[32];
        #pragma unroll
        for (int kk = 0; kk < 32; kk++) {
            wA[kk] = W[(size_t)(k0 + kk) * DD + tx];
            wB[kk] = W[(size_t)(k0 + kk) * DD + tx + 64];
        }
        #pragma unroll
        for (int kq = 0; kq < 8; kq++) {
            #pragma unroll
            for (int r = 0; r < 8; r++) {
                float4 xq = *(const float4*)&xs[(8 * wv + r) * QJ + k0 + 4 * kq];
                float xa[4] = {xq.x, xq.y, xq.z, xq.w};
                #pragma unroll
                for (int dd = 0; dd < 4; dd++) {
                    acc[r][0] += xa[dd] * wA[4 * kq + dd];
                    acc[r][1] += xa[dd] * wB[4 * kq + dd];
                }
            }
        }
    }

    const float ba = Bv[tx], bb = Bv[tx + 64];
    #pragma unroll
    for (int r = 0; r < 8; r++) {
        size_t row = (size_t)(r0 + 8 * wv + r) * DD;
        float v0 = acc[r][0] + ba;
        float v1 = acc[r][1] + bb;
        if (ACT == 0) { v0 = v0 > 0.f ? v0 : 0.f; v1 = v1 > 0.f ? v1 : 0.f; }
        else          { v0 = tanhf(v0);           v1 = tanhf(v1); }
        Y[row + tx]      = v0;
        Y[row + tx + 64] = v1;
    }
}

// ---------------------------------------------------------------------------
// prep_k: bf16 LDS-image tiles of K ([j][d], swizzled byte^=((j&7)<<4)).
// img 0..63: (b = img>>3, tile = img&7);  img 64: pe_key rows 0..127.
// ---------------------------------------------------------------------------
__global__ __launch_bounds__(256) void prep_k(const float* __restrict__ Kf,
        const float* __restrict__ PEK, char* __restrict__ kimg,
        char* __restrict__ pekimg) {
    const int img = blockIdx.x;
    const float* src;
    unsigned* dst;
    if (img < 64) {
        int b = img >> 3, tile = img & 7;
        src = Kf + ((size_t)(b * TT + tile * 128)) * DD;
        dst = (unsigned*)(kimg + (size_t)img * 32768);
    } else {
        src = PEK;
        dst = (unsigned*)pekimg;
    }
    for (int idx = threadIdx.x; idx < 8192; idx += 256) {
        int j = idx >> 6, s = idx & 63;
        int o = (4 * s) ^ ((j & 7) << 4);
        int d0 = o >> 1;
        const float* p = src + (size_t)j * DD + d0;
        dst[j * 64 + s] = packbf(p[0], p[1]);
    }
}

// ---------------------------------------------------------------------------
// prep_v: bf16 LDS-image tiles of V^T ([d][j], swizzled byte^=((d&7)<<4)).
// img 0..63: V tiles;  img 64: pe_value rows 0..127 (transposed).
// ---------------------------------------------------------------------------
__global__ __launch_bounds__(256) void prep_v(const float* __restrict__ Vf,
        const float* __restrict__ PEV, char* __restrict__ vimg,
        char* __restrict__ pevimg) {
    const int img = blockIdx.x;
    const float* src;
    unsigned* dst;
    if (img < 64) {
        int b = img >> 3, tile = img & 7;
        src = Vf + ((size_t)(b * TT + tile * 128)) * DD;
        dst = (unsigned*)(vimg + (size_t)img * 32768);
    } else {
        src = PEV;
        dst = (unsigned*)pevimg;
    }
    for (int idx = threadIdx.x; idx < 8192; idx += 256) {
        int d = idx >> 6, s = idx & 63;
        int o = (4 * s) ^ ((d & 7) << 4);
        int j0 = o >> 1;
        float a  = src[(size_t)j0 * DD + d];
        float b2 = src[(size_t)(j0 + 1) * DD + d];
        dst[d * 64 + s] = packbf(a, b2);
    }
}

// ---------------------------------------------------------------------------
// Fused attention, MFMA. Block = (batch, 16 Q rows), 512 threads, 8 waves.
// ---------------------------------------------------------------------------
__global__ __launch_bounds__(512) void attn_mfma(
        const float* __restrict__ Qm, const float* __restrict__ PEK,
        const float* __restrict__ PEV, const char* __restrict__ kimg,
        const char* __restrict__ pekimg, const char* __restrict__ vimg,
        const char* __restrict__ pevimg, float* __restrict__ Cm) {
    extern __shared__ float sm[];
    float* S   = sm;                          // [16][SJ] fp32 scores
    char*  KVb = (char*)(S + 16 * SJ);        // 32 KB staged image tile
    float* LR  = (float*)(KVb + 32768);       // [16] denominators

    const int t  = threadIdx.x;
    const int b  = blockIdx.x & 7;            // batch-major across XCDs
    const int i0 = (blockIdx.x >> 3) << 4;
    const int wv = t >> 6;
    const int l  = t & 63;

    // ---- Q fragments (A operand), same 16 rows for every wave ----
    bf16x8 qf[4];
    {
        const float* qsrc = Qm + ((size_t)b * TT + i0 + (l & 15)) * DD + ((l >> 4) << 3);
        #pragma unroll
        for (int c = 0; c < 4; c++) {
            f32x4 a0 = *(const f32x4*)(qsrc + c * 32);
            f32x4 a1 = *(const f32x4*)(qsrc + c * 32 + 4);
            u16x8 u;
            u[0] = f2bf(a0[0]); u[1] = f2bf(a0[1]); u[2] = f2bf(a0[2]); u[3] = f2bf(a0[3]);
            u[4] = f2bf(a1[0]); u[5] = f2bf(a1[1]); u[6] = f2bf(a1[2]); u[7] = f2bf(a1[3]);
            qf[c] = __builtin_bit_cast(bf16x8, u);
        }
    }

    // ---- Phase 1: extended QK -> S ----
    for (int tile = 0; tile < 9; tile++) {
        const uint4* gsrc = (const uint4*)((tile < 8)
                ? (kimg + ((size_t)b * 8 + tile) * 32768) : pekimg);
        __syncthreads();                       // prior users of KVb done
        for (int idx = t; idx < 2048; idx += 512) ((uint4*)KVb)[idx] = gsrc[idx];
        __syncthreads();

        f32x4 acc = {0.f, 0.f, 0.f, 0.f};
        const int jrow = (wv << 4) + (l & 15);
        #pragma unroll
        for (int c = 0; c < 4; c++) {
            int addr = (jrow << 8) + (c << 6) + ((l >> 4) << 4);
            addr ^= (jrow & 7) << 4;
            bf16x8 bf = *(const bf16x8*)(KVb + addr);
            acc = __builtin_amdgcn_mfma_f32_16x16x32_bf16(qf[c], bf, acc, 0, 0, 0);
        }
        const int colbase = tile * 128 + jrow;
        #pragma unroll
        for (int r = 0; r < 4; r++)
            S[(((l >> 4) << 2) + r) * SJ + colbase] = acc[r];
    }
    __syncthreads();                           // all S cols visible

    // ---- Phase 2: softmax + bucket weights (row = t>>5, 32 lanes/row) ----
    {
        const int row = t >> 5;
        const int l32 = t & 31;
        const int ig  = i0 + row;
        float* srow = S + row * SJ;

        // qpe[row][128] = Q[row] . pe_key[128]  (scalar, shfl-reduced)
        float qp;
        {
            const float* qr = Qm + ((size_t)b * TT + ig) * DD + l32 * 4;
            const float* pr = PEK + 128 * DD + l32 * 4;
            f32x4 qv = *(const f32x4*)qr;
            f32x4 pv = *(const f32x4*)pr;
            qp = qv[0] * pv[0] + qv[1] * pv[1] + qv[2] * pv[2] + qv[3] * pv[3];
            #pragma unroll
            for (int off = 16; off; off >>= 1) qp += __shfl_xor(qp, off, 64);
        }

        float lmax = -3.0e38f;
        for (int j = l32; j < TT; j += 32) {
            int idd = 64 + j - ig; idd = idd < 0 ? 0 : (idd > 128 ? 128 : idd);
            float lg = srow[j] + (idd == 128 ? qp : srow[1024 + idd]);
            srow[j] = lg;
            lmax = fmaxf(lmax, lg);
        }
        #pragma unroll
        for (int off = 16; off; off >>= 1) lmax = fmaxf(lmax, __shfl_xor(lmax, off, 64));

        for (int m = l32; m < 129; m += 32) srow[1024 + m] = 0.f;  // qpe consumed

        float lsum = 0.f, s0 = 0.f, s1 = 0.f;
        for (int j = l32; j < TT; j += 32) {
            int idd = 64 + j - ig; idd = idd < 0 ? 0 : (idd > 128 ? 128 : idd);
            float p = __expf(srow[j] - lmax);
            srow[j] = p;                       // unnormalized
            lsum += p;
            if (idd == 0)        s0 += p;
            else if (idd == 128) s1 += p;
            else                 srow[1024 + idd] = p;   // band bucket (bijective)
        }
        #pragma unroll
        for (int off = 16; off; off >>= 1) {
            lsum += __shfl_xor(lsum, off, 64);
            s0   += __shfl_xor(s0,   off, 64);
            s1   += __shfl_xor(s1,   off, 64);
        }
        if (l32 == 0) { srow[1024] = s0; srow[1024 + 128] = s1; LR[row] = lsum; }
    }

    // ---- Phase 3: C^T = V'^T . P'^T ----
    f32x4 cacc = {0.f, 0.f, 0.f, 0.f};
    for (int tile = 0; tile < 9; tile++) {
        const uint4* gsrc = (const uint4*)((tile < 8)
                ? (vimg + ((size_t)b * 8 + tile) * 32768) : pevimg);
        __syncthreads();
        for (int idx = t; idx < 2048; idx += 512) ((uint4*)KVb)[idx] = gsrc[idx];
        __syncthreads();

        const int tb = tile * 128;
        const int drow = (wv << 4) + (l & 15);
        #pragma unroll
        for (int c = 0; c < 4; c++) {
            int addr = (drow << 8) + (c << 6) + ((l >> 4) << 4);
            addr ^= (drow & 7) << 4;
            bf16x8 vf = *(const bf16x8*)(KVb + addr);     // A: V^T rows (d)
            const float* ps = S + (l & 15) * SJ + tb + c * 32 + ((l >> 4) << 3);
            f32x4 p0 = *(const f32x4*)ps;
            f32x4 p1 = *(const f32x4*)(ps + 4);
            u16x8 u;
            u[0] = f2bf(p0[0]); u[1] = f2bf(p0[1]); u[2] = f2bf(p0[2]); u[3] = f2bf(p0[3]);
            u[4] = f2bf(p1[0]); u[5] = f2bf(p1[1]); u[6] = f2bf(p1[2]); u[7] = f2bf(p1[3]);
            bf16x8 pf = __builtin_bit_cast(bf16x8, u);    // B: P^T cols (i)
            cacc = __builtin_amdgcn_mfma_f32_16x16x32_bf16(vf, pf, cacc, 0, 0, 0);
        }
    }

    // ---- epilogue: + w[128]*pe_value[128], normalize, write C ----
    {
        const int i = l & 15;
        float w128 = S[i * SJ + 1024 + 128];
        float rin  = 1.f / LR[i];
        float* dst = Cm + ((size_t)b * TT + i0 + i) * DD;
        const float* pvr = PEV + 128 * DD;
        #pragma unroll
        for (int r = 0; r < 4; r++) {
            int d = (wv << 4) + ((l >> 4) << 2) + r;
            dst[d] = (cacc[r] + w128 * pvr[d]) * rin;
        }
    }
}

// ---------------------------------------------------------------------------

extern "C" void kernel_launch(void* const* d_in, const int* in_sizes, int n_in,
                              void* d_out, int out_size, void* d_ws, size_t ws_size,
                              hipStream_t stream) {
    const float* x   = (const float*)d_in[0];
    const float* W0  = (const float*)d_in[1];
    const float* b0  = (const float*)d_in[2];
    const float* Wq  = (const float*)d_in[3];
    const float* bq  = (const float*)d_in[4];
    const float* Wk  = (const float*)d_in[5];
    const float* bk  = (const float*)d_in[6];
    const float* Wv  = (const float*)d_in[7];
    const float* bv  = (const float*)d_in[8];
    const float* W1  = (const float*)d_in[9];
    const float* b1  = (const float*)d_in[10];
    const float* pek = (const float*)d_in[11];
    const float* pev = (const float*)d_in[12];
    float* out = (float*)d_out;

    const size_t NTD = (size_t)NB * TT * DD;          // 1 Mi floats = 4 MB
    char* wsb = (char*)d_ws;
    float* hs = (float*)wsb;
    float* q  = hs + NTD;
    float* k  = q  + NTD;
    float* v  = k  + NTD;
    float* c  = v  + NTD;
    char* kimg   = wsb + 5 * NTD * sizeof(float);     // 64 x 32 KB
    char* pekimg = kimg + 64 * 32768;                 // 32 KB
    char* vimg   = pekimg + 32768;                    // 64 x 32 KB
    char* pevimg = vimg + 64 * 32768;                 // 32 KB

    const int SMEM_ATTN = (16 * SJ) * 4 + 32768 + 64; // 107,328 B
    hipFuncSetAttribute(reinterpret_cast<const void*>(attn_mfma),
                        hipFuncAttributeMaxDynamicSharedMemorySize, SMEM_ATTN);

    hipLaunchKernelGGL((gemm_act<0>), dim3(256), dim3(256), 0, stream, x,  W0, b0, hs);
    hipLaunchKernelGGL((gemm_act<1>), dim3(256), dim3(256), 0, stream, hs, Wq, bq, q);
    hipLaunchKernelGGL((gemm_act<1>), dim3(256), dim3(256), 0, stream, hs, Wk, bk, k);
    hipLaunchKernelGGL((gemm_act<1>), dim3(256), dim3(256), 0, stream, hs, Wv, bv, v);
    hipLaunchKernelGGL(prep_k, dim3(65), dim3(256), 0, stream, k, pek, kimg, pekimg);
    hipLaunchKernelGGL(prep_v, dim3(65), dim3(256), 0, stream, v, pev, vimg, pevimg);
    hipLaunchKernelGGL(attn_mfma, dim3(512), dim3(512), SMEM_ATTN, stream,
                       q, pek, pev, kimg, pekimg, vimg, pevimg, c);
    hipLaunchKernelGGL((gemm_act<0>), dim3(256), dim3(256), 0, stream, c, W1, b1, out);
}

// Round 3
// 96.739 us; speedup vs baseline: 4.1448x; 1.5025x over previous
//
#include <hip/hip_runtime.h>

// ---------------------------------------------------------------------------
// SelfAttentionRPR: B=8, T=1024, D=128, K=64, DEPTH=1, fp32 in/out.
// R3: everything on f16 MFMA (16x16x32). 256-block attn (1/CU, one round),
// 32 Q-rows/block, T14 register-prefetch staging, f16 score matrix (direct
// MFMA B-fragment reads in PV). GEMMs: 32-row blocks, one barrier, W^T f16.
// ---------------------------------------------------------------------------

#define TT 1024
#define DD 128
#define NB 8
#define SJH 1168         // S row stride (f16): pitch 2336B, /16=146 == 2 mod 8

typedef _Float16 f16;
typedef __attribute__((ext_vector_type(8))) _Float16 f16x8;
typedef __attribute__((ext_vector_type(4))) float f32x4;

static __device__ inline float fast_tanh(float x) {
    float xc = fminf(fmaxf(x, -12.f), 12.f);
    float e = __expf(2.f * xc);
    return (e - 1.f) / (e + 1.f);
}

// ---------------------------------------------------------------------------
// prep_misc: blk 0..4 -> W^T f16 (wt[n][k]); blk 5 -> pe_key rows0..127 f16;
// blk 6 -> pe_value^T f16 [d][j] (rows 0..127).
// ---------------------------------------------------------------------------
__global__ __launch_bounds__(256) void prep_misc(
        const float* __restrict__ W0, const float* __restrict__ Wq,
        const float* __restrict__ Wk, const float* __restrict__ Wv,
        const float* __restrict__ W1, const float* __restrict__ PEK,
        const float* __restrict__ PEV, f16* __restrict__ wt,
        f16* __restrict__ pek16, f16* __restrict__ pevt16) {
    const int blk = blockIdx.x, t = threadIdx.x;
    if (blk < 5) {
        const float* W = blk == 0 ? W0 : blk == 1 ? Wq : blk == 2 ? Wk
                       : blk == 3 ? Wv : W1;
        f16* o = wt + (size_t)blk * 16384;
        for (int it = 0; it < 64; it++) {
            int idx = t + 256 * it;
            int n = idx >> 7, k2 = idx & 127;
            o[n * 128 + k2] = (f16)W[k2 * 128 + n];      // transpose
        }
    } else if (blk == 5) {
        for (int it = 0; it < 64; it++) {
            int idx = t + 256 * it;
            pek16[idx] = (f16)PEK[idx];
        }
    } else if (blk == 6) {
        for (int it = 0; it < 64; it++) {
            int idx = t + 256 * it;
            int d = idx >> 7, j = idx & 127;
            pevt16[d * 128 + j] = (f16)PEV[j * 128 + d]; // transpose
        }
    }
}

// ---------------------------------------------------------------------------
// prep_v: v16 [b*1024+j][d] -> vt16 tiled [b][jt][d][j&127] via LDS transpose.
// ---------------------------------------------------------------------------
__global__ __launch_bounds__(256) void prep_v(const f16* __restrict__ v16,
                                              f16* __restrict__ vt16) {
    __shared__ __align__(16) f16 tl[128 * 132];
    const int t = threadIdx.x;
    const int b = blockIdx.x >> 3, jt = blockIdx.x & 7;
    const char* src = (const char*)(v16 + (size_t)(b * 1024 + jt * 128) * 128);
    #pragma unroll
    for (int it = 0; it < 16; it++) {               // coalesced rows -> LDS
        int idx = t + 256 * it;                     // 8-byte units, 4096 total
        int j = idx >> 5, dg = idx & 31;
        uint2 d = *(const uint2*)(src + (size_t)idx * 8);
        *(uint2*)((char*)tl + j * 264 + dg * 8) = d;
    }
    __syncthreads();
    f16* dst = vt16 + (size_t)(b * 8 + jt) * 16384;
    #pragma unroll
    for (int it = 0; it < 8; it++) {                // column gather -> coalesced
        int d = (t & 15) + 16 * it;
        int jg = t >> 4;                            // 0..15
        f16x8 o;
        #pragma unroll
        for (int e = 0; e < 8; e++) o[e] = tl[(jg * 8 + e) * 132 + d];
        *(f16x8*)(dst + d * 128 + jg * 8) = o;
    }
}

// ---------------------------------------------------------------------------
// gemm16: Y[8192,128] = act(X @ W + b), f16 MFMA. 32 rows/block, 256 thr.
// ACT: 0=relu 1=tanh. INF32: X dtype. OUTF32: Y dtype.
// ---------------------------------------------------------------------------
template<int ACT, int INF32, int OUTF32>
__global__ __launch_bounds__(256) void gemm16(const void* __restrict__ Xv,
        const f16* __restrict__ WT, const float* __restrict__ Bv,
        void* __restrict__ Yv) {
    __shared__ __align__(16) char lds[40960];       // xs 8KB @0, wt 32KB @8192
    char* xs = lds;
    char* wl = lds + 8192;
    const int t = threadIdx.x, wv = t >> 6, l = t & 63;
    const int r0 = blockIdx.x * 32;

    {   // stage W^T (linear source, XOR at ds_write)
        const char* src = (const char*)WT;
        #pragma unroll
        for (int i = 0; i < 8; i++) {
            int a = t * 128 + i * 16;
            uint4 d = *(const uint4*)(src + a);
            *(uint4*)(wl + (a ^ (((a >> 8) & 7) << 4))) = d;
        }
    }
    if (INF32) {
        const float* X = (const float*)Xv + (size_t)r0 * 128;
        #pragma unroll
        for (int i = 0; i < 2; i++) {
            f32x4 a0 = *(const f32x4*)(X + t * 16 + i * 8);
            f32x4 a1 = *(const f32x4*)(X + t * 16 + i * 8 + 4);
            f16x8 h;
            h[0]=(f16)a0[0]; h[1]=(f16)a0[1]; h[2]=(f16)a0[2]; h[3]=(f16)a0[3];
            h[4]=(f16)a1[0]; h[5]=(f16)a1[1]; h[6]=(f16)a1[2]; h[7]=(f16)a1[3];
            int a = t * 32 + i * 16;
            *(f16x8*)(xs + (a ^ (((a >> 8) & 7) << 4))) = h;
        }
    } else {
        const char* X = (const char*)Xv + (size_t)r0 * 256;
        #pragma unroll
        for (int i = 0; i < 2; i++) {
            int a = t * 32 + i * 16;
            uint4 d = *(const uint4*)(X + a);
            *(uint4*)(xs + (a ^ (((a >> 8) & 7) << 4))) = d;
        }
    }
    __syncthreads();

    f32x4 acc[2][2] = {};
    #pragma unroll
    for (int c = 0; c < 4; c++) {
        f16x8 af[2], bf[2];
        #pragma unroll
        for (int it = 0; it < 2; it++) {
            int row = it * 16 + (l & 15);
            int a = (row << 8) + (c << 6) + ((l >> 4) << 4);
            af[it] = *(const f16x8*)(xs + (a ^ ((row & 7) << 4)));
        }
        #pragma unroll
        for (int nt = 0; nt < 2; nt++) {
            int n = wv * 32 + nt * 16 + (l & 15);
            int a = (n << 8) + (c << 6) + ((l >> 4) << 4);
            bf[nt] = *(const f16x8*)(wl + (a ^ ((n & 7) << 4)));
        }
        #pragma unroll
        for (int it = 0; it < 2; it++)
            #pragma unroll
            for (int nt = 0; nt < 2; nt++)
                acc[it][nt] = __builtin_amdgcn_mfma_f32_16x16x32_f16(
                        af[it], bf[nt], acc[it][nt], 0, 0, 0);
    }

    #pragma unroll
    for (int it = 0; it < 2; it++)
        #pragma unroll
        for (int nt = 0; nt < 2; nt++) {
            int n = wv * 32 + nt * 16 + (l & 15);
            float bb = Bv[n];
            #pragma unroll
            for (int r = 0; r < 4; r++) {
                int i = it * 16 + (l >> 4) * 4 + r;
                float v = acc[it][nt][r] + bb;
                v = (ACT == 0) ? fmaxf(v, 0.f) : fast_tanh(v);
                if (OUTF32) ((float*)Yv)[(size_t)(r0 + i) * 128 + n] = v;
                else        ((f16*)Yv)[(size_t)(r0 + i) * 128 + n] = (f16)v;
            }
        }
}

// ---------------------------------------------------------------------------
// attn16: block = (batch b = blk&7, 32 Q rows), 512 threads, 8 waves.
// Phase 1: extended QK (8 K tiles + pe_key tile) -> S f16.
// Phase 2: softmax + RPR bucket fold (16 lanes/row, qpe cached in QB).
// Phase 3: C^T = V'^T P'^T (8 V tiles + pe_value tile), scalar m=128 epilogue.
// Staging: T14 register prefetch; XOR swizzle byte^=((row&7)<<4) both sides.
// ---------------------------------------------------------------------------
__global__ __launch_bounds__(512) void attn16(
        const f16* __restrict__ q16, const f16* __restrict__ k16,
        const f16* __restrict__ vt16, const f16* __restrict__ pek16,
        const f16* __restrict__ pevt16, const float* __restrict__ PEK,
        const float* __restrict__ PEV, f16* __restrict__ c16) {
    extern __shared__ __align__(16) char smraw[];
    f16*   S  = (f16*)smraw;                        // [32][SJH]
    char*  KV = smraw + 32 * SJH * 2;               // 32 KB tile
    f16*   QB = (f16*)(KV + 32768);                 // [32][132] qpe cache
    float* LR = (float*)((char*)QB + 32 * 132 * 2); // [32]

    const int t = threadIdx.x, wv = t >> 6, l = t & 63;
    const int b = blockIdx.x & 7;
    const int i0 = (blockIdx.x >> 3) << 5;

    // Q fragments: 2 i-tiles x 4 k-chunks
    f16x8 qf[2][4];
    {
        const f16* qb = q16 + ((size_t)(b * 1024 + i0 + (l & 15))) * 128 + ((l >> 4) << 3);
        #pragma unroll
        for (int it = 0; it < 2; it++)
            #pragma unroll
            for (int c = 0; c < 4; c++)
                qf[it][c] = *(const f16x8*)(qb + it * 2048 + c * 32);
    }

    uint4 st[4];
    #define LOADST(p) { const char* _s = (p); _Pragma("unroll") \
        for (int _i = 0; _i < 4; _i++) st[_i] = *(const uint4*)(_s + t * 64 + _i * 16); }
    #define WRITEKV() { _Pragma("unroll") \
        for (int _i = 0; _i < 4; _i++) { int _a = t * 64 + _i * 16; \
            *(uint4*)(KV + (_a ^ (((_a >> 8) & 7) << 4))) = st[_i]; } }

    // ---------------- Phase 1: extended QK ----------------
    LOADST((const char*)k16 + (size_t)(b * 8) * 32768);
    WRITEKV();
    __syncthreads();
    for (int tile = 0; tile < 9; tile++) {
        if (tile < 8)
            LOADST(tile < 7 ? (const char*)k16 + (size_t)(b * 8 + tile + 1) * 32768
                            : (const char*)pek16);
        const int jrow = (wv << 4) + (l & 15);
        f32x4 a0 = {0.f,0.f,0.f,0.f}, a1 = {0.f,0.f,0.f,0.f};
        #pragma unroll
        for (int c = 0; c < 4; c++) {
            int a = (jrow << 8) + (c << 6) + ((l >> 4) << 4);
            f16x8 bf = *(const f16x8*)(KV + (a ^ ((jrow & 7) << 4)));
            a0 = __builtin_amdgcn_mfma_f32_16x16x32_f16(qf[0][c], bf, a0, 0, 0, 0);
            a1 = __builtin_amdgcn_mfma_f32_16x16x32_f16(qf[1][c], bf, a1, 0, 0, 0);
        }
        const int colbase = tile * 128 + jrow;
        #pragma unroll
        for (int r = 0; r < 4; r++) {
            S[(((l >> 4) << 2) + r) * SJH + colbase]      = (f16)a0[r];
            S[(16 + ((l >> 4) << 2) + r) * SJH + colbase] = (f16)a1[r];
        }
        if (tile < 8) {
            __syncthreads();
            WRITEKV();
            __syncthreads();
        }
    }
    LOADST((const char*)vt16 + (size_t)(b * 8) * 32768);   // prefetch V tile 0
    __syncthreads();                                        // S complete

    // ---------------- Phase 2: softmax + buckets (row = t>>4) ----------------
    {
        const int row = t >> 4, l16 = t & 15;
        const int ig = i0 + row;
        f16* srow = S + row * SJH;
        f16* qrow = QB + row * 132;

        float qp;   // qpe[row][128] = Q[row] . pe_key[128]
        {
            const f16* qr = q16 + (size_t)(b * 1024 + ig) * 128 + l16 * 8;
            const float* pr = PEK + 128 * 128 + l16 * 8;
            f16x8 qv = *(const f16x8*)qr;
            float s = 0.f;
            #pragma unroll
            for (int e = 0; e < 8; e++) s += (float)qv[e] * pr[e];
            #pragma unroll
            for (int off = 8; off; off >>= 1) s += __shfl_xor(s, off, 64);
            qp = s;
        }
        for (int m = l16; m < 128; m += 16) {   // qpe S->QB, zero buckets
            qrow[m] = srow[1024 + m];
            srow[1024 + m] = (f16)0.f;
        }
        if (l16 == 0) { qrow[128] = (f16)qp; srow[1024 + 128] = (f16)0.f; }
        const float qlo = (float)qrow[0], qhi = qp;

        float lmax = -3.0e38f;
        for (int kk = 0; kk < 8; kk++) {
            int j0 = kk * 128 + l16 * 8;
            f16x8 sv = *(const f16x8*)(srow + j0);
            #pragma unroll
            for (int e = 0; e < 8; e++) {
                int idd = 64 + j0 + e - ig;
                float qv = (idd <= 0) ? qlo : (idd >= 128 ? qhi : (float)qrow[idd]);
                lmax = fmaxf(lmax, (float)sv[e] + qv);
            }
        }
        #pragma unroll
        for (int off = 8; off; off >>= 1) lmax = fmaxf(lmax, __shfl_xor(lmax, off, 64));

        float lsum = 0.f, s0 = 0.f, s1 = 0.f;
        for (int kk = 0; kk < 8; kk++) {
            int j0 = kk * 128 + l16 * 8;
            f16x8 sv = *(const f16x8*)(srow + j0);
            f16x8 pv;
            #pragma unroll
            for (int e = 0; e < 8; e++) {
                int idd = 64 + j0 + e - ig;
                float qv = (idd <= 0) ? qlo : (idd >= 128 ? qhi : (float)qrow[idd]);
                float p = __expf((float)sv[e] + qv - lmax);
                pv[e] = (f16)p;
                lsum += p;
                if (idd <= 0)        s0 += p;
                else if (idd >= 128) s1 += p;
                else                 srow[1024 + idd] = (f16)p;   // band bucket
            }
            *(f16x8*)(srow + j0) = pv;          // unnormalized P
        }
        #pragma unroll
        for (int off = 8; off; off >>= 1) {
            lsum += __shfl_xor(lsum, off, 64);
            s0   += __shfl_xor(s0,   off, 64);
            s1   += __shfl_xor(s1,   off, 64);
        }
        if (l16 == 0) {
            srow[1024] = (f16)s0;
            srow[1024 + 128] = (f16)s1;
            LR[row] = lsum;
        }
    }
    __syncthreads();
    WRITEKV();                                   // V tile 0 -> LDS
    __syncthreads();

    // ---------------- Phase 3: C^T = V'^T . P'^T ----------------
    f32x4 cacc[2] = {};
    for (int tile = 0; tile < 9; tile++) {
        if (tile < 8)
            LOADST(tile < 7 ? (const char*)vt16 + (size_t)(b * 8 + tile + 1) * 32768
                            : (const char*)pevt16);
        const int drow = (wv << 4) + (l & 15);
        const int tb = tile * 128;
        #pragma unroll
        for (int c = 0; c < 4; c++) {
            int a = (drow << 8) + (c << 6) + ((l >> 4) << 4);
            f16x8 vf = *(const f16x8*)(KV + (a ^ ((drow & 7) << 4)));
            #pragma unroll
            for (int it = 0; it < 2; it++) {
                const f16* ps = S + (it * 16 + (l & 15)) * SJH + tb + (c << 5) + ((l >> 4) << 3);
                f16x8 pf = *(const f16x8*)ps;
                cacc[it] = __builtin_amdgcn_mfma_f32_16x16x32_f16(vf, pf, cacc[it], 0, 0, 0);
            }
        }
        if (tile < 8) {
            __syncthreads();
            WRITEKV();
            __syncthreads();
        }
    }

    // ---- epilogue: + w[128]*pe_value[128], normalize, write C (f16) ----
    #pragma unroll
    for (int it = 0; it < 2; it++) {
        int i = it * 16 + (l & 15);
        float w128 = (float)S[i * SJH + 1024 + 128];
        float rin = 1.f / LR[i];
        f16* dst = c16 + (size_t)(b * 1024 + i0 + i) * 128;
        const float* pvr = PEV + 128 * 128;
        #pragma unroll
        for (int r = 0; r < 4; r++) {
            int d = (wv << 4) + ((l >> 4) << 2) + r;
            dst[d] = (f16)((cacc[it][r] + w128 * pvr[d]) * rin);
        }
    }
    #undef LOADST
    #undef WRITEKV
}

// ---------------------------------------------------------------------------

extern "C" void kernel_launch(void* const* d_in, const int* in_sizes, int n_in,
                              void* d_out, int out_size, void* d_ws, size_t ws_size,
                              hipStream_t stream) {
    const float* x   = (const float*)d_in[0];
    const float* W0  = (const float*)d_in[1];
    const float* b0  = (const float*)d_in[2];
    const float* Wq  = (const float*)d_in[3];
    const float* bq  = (const float*)d_in[4];
    const float* Wk  = (const float*)d_in[5];
    const float* bk  = (const float*)d_in[6];
    const float* Wv  = (const float*)d_in[7];
    const float* bv  = (const float*)d_in[8];
    const float* W1  = (const float*)d_in[9];
    const float* b1  = (const float*)d_in[10];
    const float* pek = (const float*)d_in[11];
    const float* pev = (const float*)d_in[12];
    float* out = (float*)d_out;

    const size_t NTD = (size_t)NB * TT * DD;   // 1,048,576 elements
    f16* hs16   = (f16*)d_ws;
    f16* q16    = hs16 + NTD;
    f16* k16a   = q16 + NTD;
    f16* v16    = k16a + NTD;
    f16* c16    = v16 + NTD;
    f16* vt16   = c16 + NTD;
    f16* wt     = vt16 + NTD;                  // 5 * 16384
    f16* pek16  = wt + 5 * 16384;              // 16384
    f16* pevt16 = pek16 + 16384;               // 16384

    const int SMEM_ATTN = 32 * SJH * 2 + 32768 + 32 * 132 * 2 + 32 * 4; // 116,096
    hipFuncSetAttribute(reinterpret_cast<const void*>(attn16),
                        hipFuncAttributeMaxDynamicSharedMemorySize, SMEM_ATTN);

    hipLaunchKernelGGL(prep_misc, dim3(7), dim3(256), 0, stream,
                       W0, Wq, Wk, Wv, W1, pek, pev, wt, pek16, pevt16);
    hipLaunchKernelGGL((gemm16<0,1,0>), dim3(256), dim3(256), 0, stream,
                       x, wt, b0, hs16);
    hipLaunchKernelGGL((gemm16<1,0,0>), dim3(256), dim3(256), 0, stream,
                       hs16, wt + 16384, bq, q16);
    hipLaunchKernelGGL((gemm16<1,0,0>), dim3(256), dim3(256), 0, stream,
                       hs16, wt + 2 * 16384, bk, k16a);
    hipLaunchKernelGGL((gemm16<1,0,0>), dim3(256), dim3(256), 0, stream,
                       hs16, wt + 3 * 16384, bv, v16);
    hipLaunchKernelGGL(prep_v, dim3(64), dim3(256), 0, stream, v16, vt16);
    hipLaunchKernelGGL(attn16, dim3(256), dim3(512), SMEM_ATTN, stream,
                       q16, k16a, vt16, pek16, pevt16, pek, pev, c16);
    hipLaunchKernelGGL((gemm16<0,0,1>), dim3(256), dim3(256), 0, stream,
                       c16, wt + 4 * 16384, b1, out);
}

// Round 4
// 76.504 us; speedup vs baseline: 5.2411x; 1.2645x over previous
//
#include <hip/hip_runtime.h>

// ---------------------------------------------------------------------------
// SelfAttentionRPR: B=8, T=1024, D=128, K=64, DEPTH=1, fp32 in/out.
// R4: barrier-free attention. K'/V' fragments read directly from global (L2,
// per-XCD batch pinning); S[16][1160] f16 in LDS; 2 syncthreads total.
// QKV projections fused into one 768-block launch (V written transposed).
// ---------------------------------------------------------------------------

#define TT 1024
#define DD 128
#define NB 8
#define SJH 1160         // S row stride (f16): 2320B = 580 dw, 580%32=4 -> 2-way

typedef _Float16 f16;
typedef __attribute__((ext_vector_type(8))) _Float16 f16x8;
typedef __attribute__((ext_vector_type(4))) _Float16 f16x4;
typedef __attribute__((ext_vector_type(4))) float f32x4;

static __device__ inline float fast_tanh(float x) {
    float xc = fminf(fmaxf(x, -12.f), 12.f);
    float e = __expf(2.f * xc);
    return (e - 1.f) / (e + 1.f);
}

// ---------------------------------------------------------------------------
// prep_misc: blk 0..4 -> W^T f16 (wt[n][k]); blk 5 -> pe_key rows 0..127 f16;
// blk 6 -> pe_value^T f16 [d][j] (rows 0..127).
// ---------------------------------------------------------------------------
__global__ __launch_bounds__(256) void prep_misc(
        const float* __restrict__ W0, const float* __restrict__ Wq,
        const float* __restrict__ Wk, const float* __restrict__ Wv,
        const float* __restrict__ W1, const float* __restrict__ PEK,
        const float* __restrict__ PEV, f16* __restrict__ wt,
        f16* __restrict__ pek16, f16* __restrict__ pevt16) {
    const int blk = blockIdx.x, t = threadIdx.x;
    if (blk < 5) {
        const float* W = blk == 0 ? W0 : blk == 1 ? Wq : blk == 2 ? Wk
                       : blk == 3 ? Wv : W1;
        f16* o = wt + (size_t)blk * 16384;
        for (int it = 0; it < 64; it++) {
            int idx = t + 256 * it;
            int n = idx >> 7, k2 = idx & 127;
            o[n * 128 + k2] = (f16)W[k2 * 128 + n];      // transpose
        }
    } else if (blk == 5) {
        for (int it = 0; it < 64; it++) {
            int idx = t + 256 * it;
            pek16[idx] = (f16)PEK[idx];
        }
    } else if (blk == 6) {
        for (int it = 0; it < 64; it++) {
            int idx = t + 256 * it;
            int d = idx >> 7, j = idx & 127;
            pevt16[d * 128 + j] = (f16)PEV[j * 128 + d]; // transpose
        }
    }
}

// ---------------------------------------------------------------------------
// gemm16: Y[8192,128] = act(X @ W + b), f16 MFMA. 32 rows/block, 256 thr.
// ACT: 0=relu 1=tanh. INF32: X dtype. OUTF32: Y dtype.  (verified R3)
// ---------------------------------------------------------------------------
template<int ACT, int INF32, int OUTF32>
__global__ __launch_bounds__(256) void gemm16(const void* __restrict__ Xv,
        const f16* __restrict__ WT, const float* __restrict__ Bv,
        void* __restrict__ Yv) {
    __shared__ __align__(16) char lds[40960];       // xs 8KB @0, wt 32KB @8192
    char* xs = lds;
    char* wl = lds + 8192;
    const int t = threadIdx.x, wv = t >> 6, l = t & 63;
    const int r0 = blockIdx.x * 32;

    {   // stage W^T (linear source, XOR at ds_write)
        const char* src = (const char*)WT;
        #pragma unroll
        for (int i = 0; i < 8; i++) {
            int a = t * 128 + i * 16;
            uint4 d = *(const uint4*)(src + a);
            *(uint4*)(wl + (a ^ (((a >> 8) & 7) << 4))) = d;
        }
    }
    if (INF32) {
        const float* X = (const float*)Xv + (size_t)r0 * 128;
        #pragma unroll
        for (int i = 0; i < 2; i++) {
            f32x4 a0 = *(const f32x4*)(X + t * 16 + i * 8);
            f32x4 a1 = *(const f32x4*)(X + t * 16 + i * 8 + 4);
            f16x8 h;
            h[0]=(f16)a0[0]; h[1]=(f16)a0[1]; h[2]=(f16)a0[2]; h[3]=(f16)a0[3];
            h[4]=(f16)a1[0]; h[5]=(f16)a1[1]; h[6]=(f16)a1[2]; h[7]=(f16)a1[3];
            int a = t * 32 + i * 16;
            *(f16x8*)(xs + (a ^ (((a >> 8) & 7) << 4))) = h;
        }
    } else {
        const char* X = (const char*)Xv + (size_t)r0 * 256;
        #pragma unroll
        for (int i = 0; i < 2; i++) {
            int a = t * 32 + i * 16;
            uint4 d = *(const uint4*)(X + a);
            *(uint4*)(xs + (a ^ (((a >> 8) & 7) << 4))) = d;
        }
    }
    __syncthreads();

    f32x4 acc[2][2] = {};
    #pragma unroll
    for (int c = 0; c < 4; c++) {
        f16x8 af[2], bf[2];
        #pragma unroll
        for (int it = 0; it < 2; it++) {
            int row = it * 16 + (l & 15);
            int a = (row << 8) + (c << 6) + ((l >> 4) << 4);
            af[it] = *(const f16x8*)(xs + (a ^ ((row & 7) << 4)));
        }
        #pragma unroll
        for (int nt = 0; nt < 2; nt++) {
            int n = wv * 32 + nt * 16 + (l & 15);
            int a = (n << 8) + (c << 6) + ((l >> 4) << 4);
            bf[nt] = *(const f16x8*)(wl + (a ^ ((n & 7) << 4)));
        }
        #pragma unroll
        for (int it = 0; it < 2; it++)
            #pragma unroll
            for (int nt = 0; nt < 2; nt++)
                acc[it][nt] = __builtin_amdgcn_mfma_f32_16x16x32_f16(
                        af[it], bf[nt], acc[it][nt], 0, 0, 0);
    }

    #pragma unroll
    for (int it = 0; it < 2; it++)
        #pragma unroll
        for (int nt = 0; nt < 2; nt++) {
            int n = wv * 32 + nt * 16 + (l & 15);
            float bb = Bv[n];
            #pragma unroll
            for (int r = 0; r < 4; r++) {
                int i = it * 16 + (l >> 4) * 4 + r;
                float v = acc[it][nt][r] + bb;
                v = (ACT == 0) ? fmaxf(v, 0.f) : fast_tanh(v);
                if (OUTF32) ((float*)Yv)[(size_t)(r0 + i) * 128 + n] = v;
                else        ((f16*)Yv)[(size_t)(r0 + i) * 128 + n] = (f16)v;
            }
        }
}

// ---------------------------------------------------------------------------
// gemm_qkv: 768 blocks; sel = blk%3 picks {Q,K,V}. Same core as gemm16.
// sel==2 writes V transposed-tiled: vt16[(i/128)*16384 + d*128 + (i&127)].
// ---------------------------------------------------------------------------
__global__ __launch_bounds__(256) void gemm_qkv(const f16* __restrict__ X,
        const f16* __restrict__ wt, const float* __restrict__ bq,
        const float* __restrict__ bk, const float* __restrict__ bv,
        f16* __restrict__ q16, f16* __restrict__ k16, f16* __restrict__ vt16) {
    __shared__ __align__(16) char lds[40960];
    char* xs = lds;
    char* wl = lds + 8192;
    const int t = threadIdx.x, wv = t >> 6, l = t & 63;
    const int sel = blockIdx.x % 3;
    const int r0 = (blockIdx.x / 3) * 32;
    const f16* WT = wt + (size_t)(sel + 1) * 16384;
    const float* Bv = sel == 0 ? bq : sel == 1 ? bk : bv;

    {
        const char* src = (const char*)WT;
        #pragma unroll
        for (int i = 0; i < 8; i++) {
            int a = t * 128 + i * 16;
            uint4 d = *(const uint4*)(src + a);
            *(uint4*)(wl + (a ^ (((a >> 8) & 7) << 4))) = d;
        }
    }
    {
        const char* Xc = (const char*)X + (size_t)r0 * 256;
        #pragma unroll
        for (int i = 0; i < 2; i++) {
            int a = t * 32 + i * 16;
            uint4 d = *(const uint4*)(Xc + a);
            *(uint4*)(xs + (a ^ (((a >> 8) & 7) << 4))) = d;
        }
    }
    __syncthreads();

    f32x4 acc[2][2] = {};
    #pragma unroll
    for (int c = 0; c < 4; c++) {
        f16x8 af[2], bf[2];
        #pragma unroll
        for (int it = 0; it < 2; it++) {
            int row = it * 16 + (l & 15);
            int a = (row << 8) + (c << 6) + ((l >> 4) << 4);
            af[it] = *(const f16x8*)(xs + (a ^ ((row & 7) << 4)));
        }
        #pragma unroll
        for (int nt = 0; nt < 2; nt++) {
            int n = wv * 32 + nt * 16 + (l & 15);
            int a = (n << 8) + (c << 6) + ((l >> 4) << 4);
            bf[nt] = *(const f16x8*)(wl + (a ^ ((n & 7) << 4)));
        }
        #pragma unroll
        for (int it = 0; it < 2; it++)
            #pragma unroll
            for (int nt = 0; nt < 2; nt++)
                acc[it][nt] = __builtin_amdgcn_mfma_f32_16x16x32_f16(
                        af[it], bf[nt], acc[it][nt], 0, 0, 0);
    }

    if (sel < 2) {
        f16* Y = sel == 0 ? q16 : k16;
        #pragma unroll
        for (int it = 0; it < 2; it++)
            #pragma unroll
            for (int nt = 0; nt < 2; nt++) {
                int n = wv * 32 + nt * 16 + (l & 15);
                float bb = Bv[n];
                #pragma unroll
                for (int r = 0; r < 4; r++) {
                    int i = it * 16 + (l >> 4) * 4 + r;
                    Y[(size_t)(r0 + i) * 128 + n] = (f16)fast_tanh(acc[it][nt][r] + bb);
                }
            }
    } else {
        #pragma unroll
        for (int it = 0; it < 2; it++)
            #pragma unroll
            for (int nt = 0; nt < 2; nt++) {
                int n = wv * 32 + nt * 16 + (l & 15);           // d
                float bb = Bv[n];
                f16x4 h;
                #pragma unroll
                for (int r = 0; r < 4; r++)
                    h[r] = (f16)fast_tanh(acc[it][nt][r] + bb);
                int jloc = (r0 & 127) + it * 16 + ((l >> 4) << 2);
                *(f16x4*)&vt16[(size_t)(r0 >> 7) * 16384 + n * 128 + jloc] = h;
            }
    }
}

// ---------------------------------------------------------------------------
// attn_v4: block = (b = blk&7 -> XCD-pinned batch, 16 Q rows), 256 thr.
// QK: A=K' (global frags), B=Q (regs) -> lane's 4 accs are j-consecutive ->
//     one ds_write_b64 per tile into S f16 [16][1160].  Waves split j-tiles.
// Softmax+bucket fold: 16 lanes/row (verified R3 logic).
// PV: C^T = V'^T P'^T; wave owns 32 d-rows; V'^T frags from global, P from S.
// 2 __syncthreads total, no staging.
// ---------------------------------------------------------------------------
__global__ __launch_bounds__(256) void attn_v4(
        const f16* __restrict__ q16, const f16* __restrict__ k16,
        const f16* __restrict__ pek16, const f16* __restrict__ vt16,
        const f16* __restrict__ pevt16, const float* __restrict__ PEK,
        const float* __restrict__ PEV, f16* __restrict__ c16) {
    __shared__ __align__(16) f16 S[16 * SJH];      // 37,120 B
    __shared__ __align__(16) f16 QB[16 * 132];     //  4,224 B
    __shared__ float LR[16];

    const int t = threadIdx.x, wv = t >> 6, l = t & 63;
    const int b = blockIdx.x & 7;
    const int i0 = (blockIdx.x >> 3) << 4;
    const int lr = l & 15, lg = l >> 4;

    // Q fragments (B operand): lane reads Q[i0+lr][lg*8 + 32c]
    f16x8 qf[4];
    {
        const f16* qb = q16 + ((size_t)(b * TT + i0 + lr)) * DD + (lg << 3);
        #pragma unroll
        for (int c = 0; c < 4; c++) qf[c] = *(const f16x8*)(qb + (c << 5));
    }

    // ---- Phase 1: QK' -> S.  Wave wv owns j-tiles jt = wv + 4m ----
    #pragma unroll 4
    for (int m = 0; m < 16; m++) {
        const int jg = (wv + (m << 2)) << 4;               // 0..1016
        const f16* asrc = k16 + ((size_t)(b * TT + jg + lr)) * DD + (lg << 3);
        f32x4 acc = {0.f, 0.f, 0.f, 0.f};
        #pragma unroll
        for (int c = 0; c < 4; c++) {
            f16x8 af = *(const f16x8*)(asrc + (c << 5));
            acc = __builtin_amdgcn_mfma_f32_16x16x32_f16(af, qf[c], acc, 0, 0, 0);
        }
        f16x4 h = {(f16)acc[0], (f16)acc[1], (f16)acc[2], (f16)acc[3]};
        *(f16x4*)&S[lr * SJH + jg + (lg << 2)] = h;
    }
    #pragma unroll
    for (int m = 16; m < 18; m++) {                        // pe_key tiles
        const int jg = (wv + (m << 2)) << 4;               // 1024..1136
        const f16* asrc = pek16 + ((size_t)(jg - 1024 + lr)) * DD + (lg << 3);
        f32x4 acc = {0.f, 0.f, 0.f, 0.f};
        #pragma unroll
        for (int c = 0; c < 4; c++) {
            f16x8 af = *(const f16x8*)(asrc + (c << 5));
            acc = __builtin_amdgcn_mfma_f32_16x16x32_f16(af, qf[c], acc, 0, 0, 0);
        }
        f16x4 h = {(f16)acc[0], (f16)acc[1], (f16)acc[2], (f16)acc[3]};
        *(f16x4*)&S[lr * SJH + jg + (lg << 2)] = h;
    }
    __syncthreads();

    // ---- Phase 2: softmax + bucket weights (row = t>>4, 16 lanes) ----
    {
        const int row = t >> 4, l16 = t & 15;
        const int ig = i0 + row;
        f16* srow = S + row * SJH;
        f16* qrow = QB + row * 132;

        float qp;   // qpe[row][128] = Q[row] . pe_key[128]
        {
            const f16* qr = q16 + (size_t)(b * TT + ig) * DD + l16 * 8;
            const float* pr = PEK + 128 * DD + l16 * 8;
            f16x8 qv = *(const f16x8*)qr;
            float s = 0.f;
            #pragma unroll
            for (int e = 0; e < 8; e++) s += (float)qv[e] * pr[e];
            #pragma unroll
            for (int off = 8; off; off >>= 1) s += __shfl_xor(s, off, 64);
            qp = s;
        }
        for (int mm = l16; mm < 128; mm += 16) {   // qpe S->QB, zero buckets
            qrow[mm] = srow[1024 + mm];
            srow[1024 + mm] = (f16)0.f;
        }
        if (l16 == 0) qrow[128] = (f16)qp;
        const float qlo = (float)qrow[0], qhi = qp;

        float lmax = -3.0e38f;
        #pragma unroll
        for (int kk = 0; kk < 8; kk++) {
            int j0 = kk * 128 + l16 * 8;
            f16x8 sv = *(const f16x8*)(srow + j0);
            #pragma unroll
            for (int e = 0; e < 8; e++) {
                int idd = 64 + j0 + e - ig;
                float qv = (idd <= 0) ? qlo : (idd >= 128 ? qhi : (float)qrow[idd]);
                lmax = fmaxf(lmax, (float)sv[e] + qv);
            }
        }
        #pragma unroll
        for (int off = 8; off; off >>= 1) lmax = fmaxf(lmax, __shfl_xor(lmax, off, 64));

        float lsum = 0.f, s0 = 0.f, s1 = 0.f;
        #pragma unroll
        for (int kk = 0; kk < 8; kk++) {
            int j0 = kk * 128 + l16 * 8;
            f16x8 sv = *(const f16x8*)(srow + j0);
            f16x8 pv;
            #pragma unroll
            for (int e = 0; e < 8; e++) {
                int idd = 64 + j0 + e - ig;
                float qv = (idd <= 0) ? qlo : (idd >= 128 ? qhi : (float)qrow[idd]);
                float p = __expf((float)sv[e] + qv - lmax);
                pv[e] = (f16)p;
                lsum += p;
                if (idd <= 0)        s0 += p;
                else if (idd >= 128) s1 += p;
                else                 srow[1024 + idd] = (f16)p;   // band bucket
            }
            *(f16x8*)(srow + j0) = pv;          // unnormalized P
        }
        #pragma unroll
        for (int off = 8; off; off >>= 1) {
            lsum += __shfl_xor(lsum, off, 64);
            s0   += __shfl_xor(s0,   off, 64);
            s1   += __shfl_xor(s1,   off, 64);
        }
        if (l16 == 0) {
            srow[1024] = (f16)s0;
            srow[1152] = (f16)s1;
            LR[row] = lsum;
        }
    }
    __syncthreads();

    // ---- Phase 3: C^T = V'^T . P'^T.  Wave wv owns d = wv*32..+31 ----
    f32x4 cacc[2] = {};
    #pragma unroll 4
    for (int jm = 0; jm < 32; jm++) {
        f16x8 pf = *(const f16x8*)&S[lr * SJH + (jm << 5) + (lg << 3)];
        const f16* vbase = vt16 + ((size_t)(b * 8 + (jm >> 2))) * 16384
                         + ((jm & 3) << 5) + (lg << 3);
        #pragma unroll
        for (int dt = 0; dt < 2; dt++) {
            int d = (wv << 5) + (dt << 4) + lr;
            f16x8 vf = *(const f16x8*)(vbase + d * 128);
            cacc[dt] = __builtin_amdgcn_mfma_f32_16x16x32_f16(vf, pf, cacc[dt], 0, 0, 0);
        }
    }
    #pragma unroll
    for (int jm = 32; jm < 36; jm++) {                     // pe_value rows
        f16x8 pf = *(const f16x8*)&S[lr * SJH + (jm << 5) + (lg << 3)];
        const f16* vbase = pevt16 + (((jm - 32) << 5) + (lg << 3));
        #pragma unroll
        for (int dt = 0; dt < 2; dt++) {
            int d = (wv << 5) + (dt << 4) + lr;
            f16x8 vf = *(const f16x8*)(vbase + d * 128);
            cacc[dt] = __builtin_amdgcn_mfma_f32_16x16x32_f16(vf, pf, cacc[dt], 0, 0, 0);
        }
    }

    // ---- epilogue: + w[128]*pe_value[128], normalize, write C ----
    {
        const float rin = 1.f / LR[lr];
        const float w128 = (float)S[lr * SJH + 1152];
        const float* pvr = PEV + 128 * DD;
        f16* dst = c16 + (size_t)(b * TT + i0 + lr) * DD;
        #pragma unroll
        for (int dt = 0; dt < 2; dt++) {
            f16x4 h;
            #pragma unroll
            for (int r = 0; r < 4; r++) {
                int d = (wv << 5) + (dt << 4) + (lg << 2) + r;
                h[r] = (f16)((cacc[dt][r] + w128 * pvr[d]) * rin);
            }
            *(f16x4*)(dst + (wv << 5) + (dt << 4) + (lg << 2)) = h;
        }
    }
}

// ---------------------------------------------------------------------------

extern "C" void kernel_launch(void* const* d_in, const int* in_sizes, int n_in,
                              void* d_out, int out_size, void* d_ws, size_t ws_size,
                              hipStream_t stream) {
    const float* x   = (const float*)d_in[0];
    const float* W0  = (const float*)d_in[1];
    const float* b0  = (const float*)d_in[2];
    const float* Wq  = (const float*)d_in[3];
    const float* bq  = (const float*)d_in[4];
    const float* Wk  = (const float*)d_in[5];
    const float* bk  = (const float*)d_in[6];
    const float* Wv  = (const float*)d_in[7];
    const float* bv  = (const float*)d_in[8];
    const float* W1  = (const float*)d_in[9];
    const float* b1  = (const float*)d_in[10];
    const float* pek = (const float*)d_in[11];
    const float* pev = (const float*)d_in[12];
    float* out = (float*)d_out;

    const size_t NTD = (size_t)NB * TT * DD;   // 1,048,576 elements
    f16* hs16   = (f16*)d_ws;
    f16* q16    = hs16 + NTD;
    f16* k16a   = q16 + NTD;
    f16* vt16   = k16a + NTD;
    f16* c16    = vt16 + NTD;
    f16* wt     = c16 + NTD;                   // 5 * 16384
    f16* pek16  = wt + 5 * 16384;              // 16384
    f16* pevt16 = pek16 + 16384;               // 16384

    hipLaunchKernelGGL(prep_misc, dim3(7), dim3(256), 0, stream,
                       W0, Wq, Wk, Wv, W1, pek, pev, wt, pek16, pevt16);
    hipLaunchKernelGGL((gemm16<0,1,0>), dim3(256), dim3(256), 0, stream,
                       x, wt, b0, hs16);
    hipLaunchKernelGGL(gemm_qkv, dim3(768), dim3(256), 0, stream,
                       hs16, wt, bq, bk, bv, q16, k16a, vt16);
    hipLaunchKernelGGL(attn_v4, dim3(512), dim3(256), 0, stream,
                       q16, k16a, pek16, vt16, pevt16, pek, pev, c16);
    hipLaunchKernelGGL((gemm16<0,0,1>), dim3(256), dim3(256), 0, stream,
                       c16, wt + 4 * 16384, b1, out);
}

// Round 5
// 57.982 us; speedup vs baseline: 6.9154x; 1.3195x over previous
//
#include <hip/hip_runtime.h>

// ---------------------------------------------------------------------------
// SelfAttentionRPR: B=8, T=1024, D=128, K=64, DEPTH=1, fp32 in/out.
// R5: attention with global_load_lds chunk streaming (pre-swizzled K/V images,
// 4-buffer counted-vmcnt pipeline, raw s_barrier), 32 Q-rows/block, 256 blocks.
// K image: [j][d] chunks of 64 j-rows, byte^=((j&7)<<4) within 256B rows.
// V image: [d][j] chunks of 64 j-cols, byte^=((d&7)<<4) within 128B rows.
// ---------------------------------------------------------------------------

#define TT 1024
#define DD 128
#define NB 8
#define SJH 1160         // S row stride (f16): 2320B = 580 dw; 580%32=4 -> 2-way

typedef _Float16 f16;
typedef __attribute__((ext_vector_type(8))) _Float16 f16x8;
typedef __attribute__((ext_vector_type(4))) _Float16 f16x4;
typedef __attribute__((ext_vector_type(4))) float f32x4;

static __device__ inline float fast_tanh(float x) {
    float xc = fminf(fmaxf(x, -12.f), 12.f);
    float e = __expf(2.f * xc);
    return (e - 1.f) / (e + 1.f);
}

// ---------------------------------------------------------------------------
// prep_misc: blk 0..4 -> W^T f16 (wt[n][k]); blk 5 -> pe_key image rows 0..127
// ([j][d] swizzled); blk 6 -> pe_value image rows 0..127 ([d][j] swizzled).
// ---------------------------------------------------------------------------
__global__ __launch_bounds__(256) void prep_misc(
        const float* __restrict__ W0, const float* __restrict__ Wq,
        const float* __restrict__ Wk, const float* __restrict__ Wv,
        const float* __restrict__ W1, const float* __restrict__ PEK,
        const float* __restrict__ PEV, f16* __restrict__ wt,
        char* __restrict__ pekimg, char* __restrict__ pevimg) {
    const int blk = blockIdx.x, t = threadIdx.x;
    if (blk < 5) {
        const float* W = blk == 0 ? W0 : blk == 1 ? Wq : blk == 2 ? Wk
                       : blk == 3 ? Wv : W1;
        f16* o = wt + (size_t)blk * 16384;
        for (int it = 0; it < 64; it++) {
            int idx = t + 256 * it;
            int n = idx >> 7, k2 = idx & 127;
            o[n * 128 + k2] = (f16)W[k2 * 128 + n];      // transpose
        }
    } else if (blk == 5) {
        for (int it = 0; it < 64; it++) {
            int idx = t + 256 * it;                      // 16384 elements
            int m = idx >> 7, d = idx & 127;             // pe rows 0..127
            char* dst = pekimg + (m >> 6) * 16384 + (m & 63) * 256
                      + ((2 * d) ^ ((m & 7) << 4));
            *(f16*)dst = (f16)PEK[m * 128 + d];
        }
    } else if (blk == 6) {
        for (int it = 0; it < 64; it++) {
            int idx = t + 256 * it;
            int m = idx >> 7, d = idx & 127;
            char* dst = pevimg + (m >> 6) * 16384 + d * 128
                      + ((2 * (m & 63)) ^ ((d & 7) << 4));
            *(f16*)dst = (f16)PEV[m * 128 + d];
        }
    }
}

// ---------------------------------------------------------------------------
// gemm16: Y[8192,128] = act(X @ W + b), f16 MFMA. 32 rows/block, 256 thr.
// ACT: 0=relu 1=tanh. INF32: X dtype. OUTF32: Y dtype.  (verified R3/R4)
// ---------------------------------------------------------------------------
template<int ACT, int INF32, int OUTF32>
__global__ __launch_bounds__(256) void gemm16(const void* __restrict__ Xv,
        const f16* __restrict__ WT, const float* __restrict__ Bv,
        void* __restrict__ Yv) {
    __shared__ __align__(16) char lds[40960];       // xs 8KB @0, wt 32KB @8192
    char* xs = lds;
    char* wl = lds + 8192;
    const int t = threadIdx.x, wv = t >> 6, l = t & 63;
    const int r0 = blockIdx.x * 32;

    {   // stage W^T (linear source, XOR at ds_write)
        const char* src = (const char*)WT;
        #pragma unroll
        for (int i = 0; i < 8; i++) {
            int a = t * 128 + i * 16;
            uint4 d = *(const uint4*)(src + a);
            *(uint4*)(wl + (a ^ (((a >> 8) & 7) << 4))) = d;
        }
    }
    if (INF32) {
        const float* X = (const float*)Xv + (size_t)r0 * 128;
        #pragma unroll
        for (int i = 0; i < 2; i++) {
            f32x4 a0 = *(const f32x4*)(X + t * 16 + i * 8);
            f32x4 a1 = *(const f32x4*)(X + t * 16 + i * 8 + 4);
            f16x8 h;
            h[0]=(f16)a0[0]; h[1]=(f16)a0[1]; h[2]=(f16)a0[2]; h[3]=(f16)a0[3];
            h[4]=(f16)a1[0]; h[5]=(f16)a1[1]; h[6]=(f16)a1[2]; h[7]=(f16)a1[3];
            int a = t * 32 + i * 16;
            *(f16x8*)(xs + (a ^ (((a >> 8) & 7) << 4))) = h;
        }
    } else {
        const char* X = (const char*)Xv + (size_t)r0 * 256;
        #pragma unroll
        for (int i = 0; i < 2; i++) {
            int a = t * 32 + i * 16;
            uint4 d = *(const uint4*)(X + a);
            *(uint4*)(xs + (a ^ (((a >> 8) & 7) << 4))) = d;
        }
    }
    __syncthreads();

    f32x4 acc[2][2] = {};
    #pragma unroll
    for (int c = 0; c < 4; c++) {
        f16x8 af[2], bf[2];
        #pragma unroll
        for (int it = 0; it < 2; it++) {
            int row = it * 16 + (l & 15);
            int a = (row << 8) + (c << 6) + ((l >> 4) << 4);
            af[it] = *(const f16x8*)(xs + (a ^ ((row & 7) << 4)));
        }
        #pragma unroll
        for (int nt = 0; nt < 2; nt++) {
            int n = wv * 32 + nt * 16 + (l & 15);
            int a = (n << 8) + (c << 6) + ((l >> 4) << 4);
            bf[nt] = *(const f16x8*)(wl + (a ^ ((n & 7) << 4)));
        }
        #pragma unroll
        for (int it = 0; it < 2; it++)
            #pragma unroll
            for (int nt = 0; nt < 2; nt++)
                acc[it][nt] = __builtin_amdgcn_mfma_f32_16x16x32_f16(
                        af[it], bf[nt], acc[it][nt], 0, 0, 0);
    }

    #pragma unroll
    for (int it = 0; it < 2; it++)
        #pragma unroll
        for (int nt = 0; nt < 2; nt++) {
            int n = wv * 32 + nt * 16 + (l & 15);
            float bb = Bv[n];
            #pragma unroll
            for (int r = 0; r < 4; r++) {
                int i = it * 16 + (l >> 4) * 4 + r;
                float v = acc[it][nt][r] + bb;
                v = (ACT == 0) ? fmaxf(v, 0.f) : fast_tanh(v);
                if (OUTF32) ((float*)Yv)[(size_t)(r0 + i) * 128 + n] = v;
                else        ((f16*)Yv)[(size_t)(r0 + i) * 128 + n] = (f16)v;
            }
        }
}

// ---------------------------------------------------------------------------
// gemm_qkv: 768 blocks; sel = blk%3 picks {Q,K,V}. Same MFMA core.
// sel==0: Q plain [i][d].  sel==1: K image (LDS-bounce -> [j][d] swizzled
// 16KB chunks).  sel==2: V image (direct swizzled f16x4 -> [d][j] chunks).
// ---------------------------------------------------------------------------
__global__ __launch_bounds__(256) void gemm_qkv(const f16* __restrict__ X,
        const f16* __restrict__ wt, const float* __restrict__ bq,
        const float* __restrict__ bk, const float* __restrict__ bv,
        f16* __restrict__ q16, char* __restrict__ kimg, char* __restrict__ vimg) {
    __shared__ __align__(16) char lds[40960];
    char* xs = lds;
    char* wl = lds + 8192;
    const int t = threadIdx.x, wv = t >> 6, l = t & 63;
    const int sel = blockIdx.x % 3;
    const int r0 = (blockIdx.x / 3) * 32;
    const f16* WT = wt + (size_t)(sel + 1) * 16384;
    const float* Bv = sel == 0 ? bq : sel == 1 ? bk : bv;

    {
        const char* src = (const char*)WT;
        #pragma unroll
        for (int i = 0; i < 8; i++) {
            int a = t * 128 + i * 16;
            uint4 d = *(const uint4*)(src + a);
            *(uint4*)(wl + (a ^ (((a >> 8) & 7) << 4))) = d;
        }
    }
    {
        const char* Xc = (const char*)X + (size_t)r0 * 256;
        #pragma unroll
        for (int i = 0; i < 2; i++) {
            int a = t * 32 + i * 16;
            uint4 d = *(const uint4*)(Xc + a);
            *(uint4*)(xs + (a ^ (((a >> 8) & 7) << 4))) = d;
        }
    }
    __syncthreads();

    f32x4 acc[2][2] = {};
    #pragma unroll
    for (int c = 0; c < 4; c++) {
        f16x8 af[2], bf[2];
        #pragma unroll
        for (int it = 0; it < 2; it++) {
            int row = it * 16 + (l & 15);
            int a = (row << 8) + (c << 6) + ((l >> 4) << 4);
            af[it] = *(const f16x8*)(xs + (a ^ ((row & 7) << 4)));
        }
        #pragma unroll
        for (int nt = 0; nt < 2; nt++) {
            int n = wv * 32 + nt * 16 + (l & 15);
            int a = (n << 8) + (c << 6) + ((l >> 4) << 4);
            bf[nt] = *(const f16x8*)(wl + (a ^ ((n & 7) << 4)));
        }
        #pragma unroll
        for (int it = 0; it < 2; it++)
            #pragma unroll
            for (int nt = 0; nt < 2; nt++)
                acc[it][nt] = __builtin_amdgcn_mfma_f32_16x16x32_f16(
                        af[it], bf[nt], acc[it][nt], 0, 0, 0);
    }

    if (sel == 0) {
        #pragma unroll
        for (int it = 0; it < 2; it++)
            #pragma unroll
            for (int nt = 0; nt < 2; nt++) {
                int n = wv * 32 + nt * 16 + (l & 15);
                float bb = Bv[n];
                #pragma unroll
                for (int r = 0; r < 4; r++) {
                    int i = it * 16 + (l >> 4) * 4 + r;
                    q16[(size_t)(r0 + i) * 128 + n] = (f16)fast_tanh(acc[it][nt][r] + bb);
                }
            }
    } else if (sel == 1) {
        __syncthreads();                     // xs/wl reads done; reuse as ts
        f16* ts = (f16*)lds;                 // [32][128]
        #pragma unroll
        for (int it = 0; it < 2; it++)
            #pragma unroll
            for (int nt = 0; nt < 2; nt++) {
                int n = wv * 32 + nt * 16 + (l & 15);
                float bb = Bv[n];
                #pragma unroll
                for (int r = 0; r < 4; r++) {
                    int i = it * 16 + (l >> 4) * 4 + r;
                    ts[i * 128 + n] = (f16)fast_tanh(acc[it][nt][r] + bb);
                }
            }
        __syncthreads();
        #pragma unroll
        for (int half = 0; half < 2; half++) {
            int row = (t >> 4) + half * 16, seg = t & 15;
            int jg = r0 + row, jp = jg & 63;
            char* dst = kimg + (size_t)((jg >> 10) * 16 + ((jg & 1023) >> 6)) * 16384
                      + jp * 256 + ((seg * 16) ^ ((jp & 7) << 4));
            *(f16x8*)dst = *(const f16x8*)&ts[row * 128 + seg * 8];
        }
    } else {
        #pragma unroll
        for (int it = 0; it < 2; it++)
            #pragma unroll
            for (int nt = 0; nt < 2; nt++) {
                int n = wv * 32 + nt * 16 + (l & 15);       // d
                float bb = Bv[n];
                f16x4 h;
                #pragma unroll
                for (int r = 0; r < 4; r++)
                    h[r] = (f16)fast_tanh(acc[it][nt][r] + bb);
                int jb = r0 + it * 16 + ((l >> 4) << 2);    // 4-aligned j run
                char* dst = vimg + (size_t)((jb >> 10) * 16 + ((jb & 1023) >> 6)) * 16384
                          + n * 128 + ((2 * (jb & 63)) ^ ((n & 7) << 4));
                *(f16x4*)dst = h;
            }
    }
}

// ---------------------------------------------------------------------------
// attn_v5: block = (b = blk&7 XCD-pinned, 32 Q rows), 512 thr / 8 waves.
// 18 chunks x 16KB per phase streamed via global_load_lds into 4 LDS buffers;
// counted vmcnt(4) + raw s_barrier (1 barrier/chunk, loads span barriers).
// Wave roles: phase1 (it = wv&1, jsub = wv>>1), phase3 (d-group = wv).
// ---------------------------------------------------------------------------
#define ISSUE(src, bi) do {                                                      \
    const char* _g = (src) + t * 16;                                             \
    char* _d = BUF + (bi) * 16384 + t * 16;                                      \
    __builtin_amdgcn_global_load_lds(                                            \
        (const __attribute__((address_space(1))) unsigned*)_g,                   \
        (__attribute__((address_space(3))) unsigned*)_d, 16, 0, 0);              \
    __builtin_amdgcn_global_load_lds(                                            \
        (const __attribute__((address_space(1))) unsigned*)(_g + 8192),          \
        (__attribute__((address_space(3))) unsigned*)(_d + 8192), 16, 0, 0);     \
} while (0)

__global__ __launch_bounds__(512) void attn_v5(
        const f16* __restrict__ q16, const char* __restrict__ kimg,
        const char* __restrict__ pekimg, const char* __restrict__ vimg,
        const char* __restrict__ pevimg, const float* __restrict__ PEK,
        const float* __restrict__ PEV, f16* __restrict__ c16) {
    extern __shared__ __align__(16) char sm5[];
    f16*   S   = (f16*)sm5;                            // 32*1160*2 = 74240
    char*  BUF = sm5 + 74240;                          // 4 x 16384
    f16*   QB  = (f16*)(sm5 + 74240 + 65536);          // 32*132*2 = 8448
    float* LR  = (float*)(sm5 + 74240 + 65536 + 8448); // 32 floats

    const int t = threadIdx.x, wv = t >> 6, l = t & 63;
    const int lr = l & 15, lg = l >> 4;
    const int b = blockIdx.x & 7;
    const int i0 = (blockIdx.x >> 3) << 5;
    const int it = wv & 1, jsub = wv >> 1;

    // Q fragments for this wave's i-half (B operand of QK)
    f16x8 qf[4];
    {
        const f16* qb = q16 + (size_t)(b * 1024 + i0 + it * 16 + lr) * 128 + lg * 8;
        #pragma unroll
        for (int c = 0; c < 4; c++) qf[c] = *(const f16x8*)(qb + c * 32);
    }

    const char* kbase = kimg + (size_t)b * 16 * 16384;
    const char* vbase = vimg + (size_t)b * 16 * 16384;

    ISSUE(kbase, 0);
    ISSUE(kbase + 16384, 1);

    // ---------------- Phase 1: extended QK -> S ----------------
    for (int ch = 0; ch < 18; ch++) {
        if (ch < 14)      ISSUE(kbase + (size_t)(ch + 2) * 16384, (ch + 2) & 3);
        else if (ch < 16) ISSUE(pekimg + (size_t)(ch - 14) * 16384, (ch + 2) & 3);
        else              ISSUE(vbase + (size_t)(ch - 16) * 16384, (ch + 2) & 3);
        asm volatile("s_waitcnt vmcnt(4)" ::: "memory");
        __builtin_amdgcn_s_barrier();
        __builtin_amdgcn_sched_barrier(0);

        const char* kb = BUF + (ch & 3) * 16384;
        const int jp = jsub * 16 + lr;
        f32x4 acc = {0.f, 0.f, 0.f, 0.f};
        #pragma unroll
        for (int c = 0; c < 4; c++) {
            f16x8 kf = *(const f16x8*)(kb + jp * 256 + ((c * 64 + lg * 16) ^ ((jp & 7) << 4)));
            acc = __builtin_amdgcn_mfma_f32_16x16x32_f16(kf, qf[c], acc, 0, 0, 0);
        }
        f16x4 h = {(f16)acc[0], (f16)acc[1], (f16)acc[2], (f16)acc[3]};
        *(f16x4*)&S[(it * 16 + lr) * SJH + ch * 64 + jsub * 16 + lg * 4] = h;
    }
    asm volatile("s_waitcnt lgkmcnt(0)" ::: "memory");
    __builtin_amdgcn_s_barrier();
    __builtin_amdgcn_sched_barrier(0);

    // ---------------- Phase 2: softmax + buckets (row = t>>4) ----------------
    {
        const int row = t >> 4, l16 = t & 15;
        const int ig = i0 + row;
        f16* srow = S + row * SJH;
        f16* qrow = QB + row * 132;

        float qp;   // qpe[row][128] = Q[row] . pe_key[128]
        {
            const f16* qr = q16 + (size_t)(b * 1024 + ig) * 128 + l16 * 8;
            const float* pr = PEK + 128 * 128 + l16 * 8;
            f16x8 qv = *(const f16x8*)qr;
            float s = 0.f;
            #pragma unroll
            for (int e = 0; e < 8; e++) s += (float)qv[e] * pr[e];
            #pragma unroll
            for (int off = 8; off; off >>= 1) s += __shfl_xor(s, off, 64);
            qp = s;
        }
        for (int mm = l16; mm < 128; mm += 16) {   // qpe S->QB, zero buckets
            qrow[mm] = srow[1024 + mm];
            srow[1024 + mm] = (f16)0.f;
        }
        if (l16 == 0) qrow[128] = (f16)qp;
        const float qlo = (float)qrow[0], qhi = qp;

        float lmax = -3.0e38f;
        #pragma unroll
        for (int kk = 0; kk < 8; kk++) {
            int j0 = kk * 128 + l16 * 8;
            f16x8 sv = *(const f16x8*)(srow + j0);
            #pragma unroll
            for (int e = 0; e < 8; e++) {
                int idd = 64 + j0 + e - ig;
                float qv = (idd <= 0) ? qlo : (idd >= 128 ? qhi : (float)qrow[idd]);
                lmax = fmaxf(lmax, (float)sv[e] + qv);
            }
        }
        #pragma unroll
        for (int off = 8; off; off >>= 1) lmax = fmaxf(lmax, __shfl_xor(lmax, off, 64));

        float lsum = 0.f, s0 = 0.f, s1 = 0.f;
        #pragma unroll
        for (int kk = 0; kk < 8; kk++) {
            int j0 = kk * 128 + l16 * 8;
            f16x8 sv = *(const f16x8*)(srow + j0);
            f16x8 pv;
            #pragma unroll
            for (int e = 0; e < 8; e++) {
                int idd = 64 + j0 + e - ig;
                float qv = (idd <= 0) ? qlo : (idd >= 128 ? qhi : (float)qrow[idd]);
                float p = __expf((float)sv[e] + qv - lmax);
                pv[e] = (f16)p;
                lsum += p;
                if (idd <= 0)        s0 += p;
                else if (idd >= 128) s1 += p;
                else                 srow[1024 + idd] = (f16)p;   // band bucket
            }
            *(f16x8*)(srow + j0) = pv;          // unnormalized P
        }
        #pragma unroll
        for (int off = 8; off; off >>= 1) {
            lsum += __shfl_xor(lsum, off, 64);
            s0   += __shfl_xor(s0,   off, 64);
            s1   += __shfl_xor(s1,   off, 64);
        }
        if (l16 == 0) {
            srow[1024] = (f16)s0;
            srow[1152] = (f16)s1;
            LR[row] = lsum;
        }
    }
    asm volatile("s_waitcnt lgkmcnt(0)" ::: "memory");
    __builtin_amdgcn_s_barrier();
    __builtin_amdgcn_sched_barrier(0);

    // ---------------- Phase 3: C^T = V'^T . P'^T ----------------
    f32x4 cacc[2] = {};
    for (int ch = 0; ch < 18; ch++) {
        if (ch < 14) {
            ISSUE(vbase + (size_t)(ch + 2) * 16384, (ch + 4) & 3);
            asm volatile("s_waitcnt vmcnt(4)" ::: "memory");
        } else if (ch < 16) {
            ISSUE(pevimg + (size_t)(ch - 14) * 16384, (ch + 4) & 3);
            asm volatile("s_waitcnt vmcnt(4)" ::: "memory");
        } else if (ch == 16) {
            asm volatile("s_waitcnt vmcnt(2)" ::: "memory");
        } else {
            asm volatile("s_waitcnt vmcnt(0)" ::: "memory");
        }
        __builtin_amdgcn_s_barrier();
        __builtin_amdgcn_sched_barrier(0);

        const char* vb = BUF + ((ch + 2) & 3) * 16384;
        const int dp = wv * 16 + lr;
        #pragma unroll
        for (int c2 = 0; c2 < 2; c2++) {
            f16x8 vf = *(const f16x8*)(vb + dp * 128 + ((c2 * 64 + lg * 16) ^ ((dp & 7) << 4)));
            #pragma unroll
            for (int i2 = 0; i2 < 2; i2++) {
                f16x8 pf = *(const f16x8*)&S[(i2 * 16 + lr) * SJH + ch * 64 + c2 * 32 + lg * 8];
                cacc[i2] = __builtin_amdgcn_mfma_f32_16x16x32_f16(vf, pf, cacc[i2], 0, 0, 0);
            }
        }
    }

    // ---- epilogue: + w[128]*pe_value[128], normalize, write C ----
    #pragma unroll
    for (int i2 = 0; i2 < 2; i2++) {
        const int irow = i2 * 16 + lr;
        const float w128 = (float)S[irow * SJH + 1152];
        const float rin = 1.f / LR[irow];
        const float* pvr = PEV + 128 * 128;
        f16x4 h;
        #pragma unroll
        for (int r = 0; r < 4; r++) {
            int d = wv * 16 + lg * 4 + r;
            h[r] = (f16)((cacc[i2][r] + w128 * pvr[d]) * rin);
        }
        *(f16x4*)(c16 + (size_t)(b * 1024 + i0 + irow) * 128 + wv * 16 + lg * 4) = h;
    }
}

// ---------------------------------------------------------------------------

extern "C" void kernel_launch(void* const* d_in, const int* in_sizes, int n_in,
                              void* d_out, int out_size, void* d_ws, size_t ws_size,
                              hipStream_t stream) {
    const float* x   = (const float*)d_in[0];
    const float* W0  = (const float*)d_in[1];
    const float* b0  = (const float*)d_in[2];
    const float* Wq  = (const float*)d_in[3];
    const float* bq  = (const float*)d_in[4];
    const float* Wk  = (const float*)d_in[5];
    const float* bk  = (const float*)d_in[6];
    const float* Wv  = (const float*)d_in[7];
    const float* bv  = (const float*)d_in[8];
    const float* W1  = (const float*)d_in[9];
    const float* b1  = (const float*)d_in[10];
    const float* pek = (const float*)d_in[11];
    const float* pev = (const float*)d_in[12];
    float* out = (float*)d_out;

    const size_t NTD = (size_t)NB * TT * DD;   // 1,048,576 elements
    f16* hs16 = (f16*)d_ws;
    f16* q16  = hs16 + NTD;
    f16* c16  = q16 + NTD;
    f16* wt   = c16 + NTD;                     // 5 * 16384 f16
    char* kimg   = (char*)(wt + 5 * 16384);    // 8*16*16384 B = 2 MB
    char* vimg   = kimg + (size_t)8 * 16 * 16384;
    char* pekimg = vimg + (size_t)8 * 16 * 16384;   // 32 KB
    char* pevimg = pekimg + 32768;                  // 32 KB

    const int SMEM_ATTN = 74240 + 65536 + 8448 + 128;   // 148,352 B
    hipFuncSetAttribute(reinterpret_cast<const void*>(attn_v5),
                        hipFuncAttributeMaxDynamicSharedMemorySize, SMEM_ATTN);

    hipLaunchKernelGGL(prep_misc, dim3(7), dim3(256), 0, stream,
                       W0, Wq, Wk, Wv, W1, pek, pev, wt, pekimg, pevimg);
    hipLaunchKernelGGL((gemm16<0,1,0>), dim3(256), dim3(256), 0, stream,
                       x, wt, b0, hs16);
    hipLaunchKernelGGL(gemm_qkv, dim3(768), dim3(256), 0, stream,
                       hs16, wt, bq, bk, bv, q16, kimg, vimg);
    hipLaunchKernelGGL(attn_v5, dim3(256), dim3(512), SMEM_ATTN, stream,
                       q16, kimg, pekimg, vimg, pevimg, pek, pev, c16);
    hipLaunchKernelGGL((gemm16<0,0,1>), dim3(256), dim3(256), 0, stream,
                       c16, wt + 4 * 16384, b1, out);
}

// Round 6
// 56.488 us; speedup vs baseline: 7.0983x; 1.0264x over previous
//
#include <hip/hip_runtime.h>

// ---------------------------------------------------------------------------
// SelfAttentionRPR: B=8, T=1024, D=128, K=64, DEPTH=1, fp32 in/out.
// R6: 3 kernels total.
//  prep_w:    W^T f16 (5 matrices).
//  fused_qkv: fc0 + Q/K/V projections in one kernel (hs stays in LDS);
//             K/V written as pre-swizzled 32KB attention chunks; 2 extra
//             blocks build pe_key / pe_value images.
//  attn_all:  32KB-chunk global_load_lds streaming (2 buffers, wait->barrier
//             ->issue), softmax+RPR fold, PV, and the final C@W1+b1 GEMM
//             fused in the tail (BUF reused for W1^T, S reused for c-tile).
// K chunk: [j&127][d] rows 256B, byte^=((j&7)<<4).
// V chunk: [d][j&127] rows 256B, byte^=((d&7)<<4).
// ---------------------------------------------------------------------------

#define TT 1024
#define DD 128
#define NB 8
#define SJH 1160         // S row stride (f16)

typedef _Float16 f16;
typedef __attribute__((ext_vector_type(8))) _Float16 f16x8;
typedef __attribute__((ext_vector_type(4))) _Float16 f16x4;
typedef __attribute__((ext_vector_type(4))) float f32x4;

static __device__ inline float fast_tanh(float x) {
    float xc = fminf(fmaxf(x, -12.f), 12.f);
    float e = __expf(2.f * xc);
    return (e - 1.f) / (e + 1.f);
}

// ---------------------------------------------------------------------------
__global__ __launch_bounds__(256) void prep_w(
        const float* __restrict__ W0, const float* __restrict__ Wq,
        const float* __restrict__ Wk, const float* __restrict__ Wv,
        const float* __restrict__ W1, f16* __restrict__ wt) {
    const int blk = blockIdx.x, t = threadIdx.x;
    const float* W = blk == 0 ? W0 : blk == 1 ? Wq : blk == 2 ? Wk
                   : blk == 3 ? Wv : W1;
    f16* o = wt + (size_t)blk * 16384;
    for (int it = 0; it < 64; it++) {
        int idx = t + 256 * it;
        int n = idx >> 7, k2 = idx & 127;
        o[n * 128 + k2] = (f16)W[k2 * 128 + n];          // transpose
    }
}

// ---------------------------------------------------------------------------
#define STAGEW(s) do { const char* _src = (const char*)(wt + (size_t)(s) * 16384); \
    _Pragma("unroll") for (int _i = 0; _i < 8; _i++) { \
        int _a = t * 128 + _i * 16; uint4 _d = *(const uint4*)(_src + _a); \
        *(uint4*)(wl + (_a ^ (((_a >> 8) & 7) << 4))) = _d; } } while (0)

#define ZACC() do { _Pragma("unroll") for (int _i = 0; _i < 2; _i++) \
    _Pragma("unroll") for (int _j = 0; _j < 2; _j++) \
        acc[_i][_j] = (f32x4){0.f, 0.f, 0.f, 0.f}; } while (0)

#define GEMMCORE(SRC) do { \
    _Pragma("unroll") for (int _c = 0; _c < 4; _c++) { \
        f16x8 _af[2], _bf[2]; \
        _Pragma("unroll") for (int _it = 0; _it < 2; _it++) { \
            int _row = _it * 16 + (l & 15); \
            int _a = (_row << 8) + (_c << 6) + ((l >> 4) << 4); \
            _af[_it] = *(const f16x8*)((SRC) + (_a ^ ((_row & 7) << 4))); } \
        _Pragma("unroll") for (int _nt = 0; _nt < 2; _nt++) { \
            int _n = wv * 32 + _nt * 16 + (l & 15); \
            int _a = (_n << 8) + (_c << 6) + ((l >> 4) << 4); \
            _bf[_nt] = *(const f16x8*)(wl + (_a ^ ((_n & 7) << 4))); } \
        _Pragma("unroll") for (int _it = 0; _it < 2; _it++) \
        _Pragma("unroll") for (int _nt = 0; _nt < 2; _nt++) \
            acc[_it][_nt] = __builtin_amdgcn_mfma_f32_16x16x32_f16( \
                    _af[_it], _bf[_nt], acc[_it][_nt], 0, 0, 0); } } while (0)

// fused_qkv: blocks 0..255 = 32-row GEMM chain; 256/257 = pe images.
__global__ __launch_bounds__(256) void fused_qkv(
        const float* __restrict__ x, const f16* __restrict__ wt,
        const float* __restrict__ b0, const float* __restrict__ bq,
        const float* __restrict__ bk, const float* __restrict__ bv,
        const float* __restrict__ PEK, const float* __restrict__ PEV,
        f16* __restrict__ q16, char* __restrict__ kimg,
        char* __restrict__ vimg, char* __restrict__ pekimg,
        char* __restrict__ pevimg) {
    __shared__ __align__(16) char lds[49152];
    char* xs  = lds;            // 8KB  x-tile / k-bounce
    char* hsl = lds + 8192;     // 8KB  hs-tile
    char* wl  = lds + 16384;    // 32KB W^T
    const int t = threadIdx.x, wv = t >> 6, l = t & 63;
    const int blk = blockIdx.x;

    if (blk >= 256) {                            // pe image builders
        if (blk == 256) {
            for (int it = 0; it < 64; it++) {
                int idx = t + 256 * it;          // 128 rows x 128 d
                int m = idx >> 7, d = idx & 127;
                *(f16*)(pekimg + m * 256 + ((2 * d) ^ ((m & 7) << 4))) =
                        (f16)PEK[m * 128 + d];
            }
        } else {
            for (int it = 0; it < 64; it++) {
                int idx = t + 256 * it;
                int m = idx >> 7, d = idx & 127;
                *(f16*)(pevimg + d * 256 + ((2 * m) ^ ((d & 7) << 4))) =
                        (f16)PEV[m * 128 + d];
            }
        }
        return;
    }

    const int r0 = blk * 32;
    // stage x (fp32 -> f16, swizzled)
    {
        const float* X = x + (size_t)r0 * 128;
        #pragma unroll
        for (int i = 0; i < 2; i++) {
            f32x4 a0 = *(const f32x4*)(X + t * 16 + i * 8);
            f32x4 a1 = *(const f32x4*)(X + t * 16 + i * 8 + 4);
            f16x8 h;
            h[0]=(f16)a0[0]; h[1]=(f16)a0[1]; h[2]=(f16)a0[2]; h[3]=(f16)a0[3];
            h[4]=(f16)a1[0]; h[5]=(f16)a1[1]; h[6]=(f16)a1[2]; h[7]=(f16)a1[3];
            int a = t * 32 + i * 16;
            *(f16x8*)(xs + (a ^ (((a >> 8) & 7) << 4))) = h;
        }
    }
    STAGEW(0);
    __syncthreads();

    f32x4 acc[2][2];
    ZACC();
    GEMMCORE(xs);                                // hs = relu(x@W0+b0)
    __syncthreads();                             // wl0/xs reads done
    {
        #pragma unroll
        for (int it = 0; it < 2; it++)
            #pragma unroll
            for (int nt = 0; nt < 2; nt++) {
                int n = wv * 32 + nt * 16 + (l & 15);
                float bb = b0[n];
                #pragma unroll
                for (int r = 0; r < 4; r++) {
                    int i = it * 16 + (l >> 4) * 4 + r;
                    float v = fmaxf(acc[it][nt][r] + bb, 0.f);
                    int a = i * 256 + 2 * n;
                    *(f16*)(hsl + (a ^ ((i & 7) << 4))) = (f16)v;
                }
            }
    }
    STAGEW(1);
    __syncthreads();

    ZACC();
    GEMMCORE(hsl);                               // q = tanh(hs@Wq+bq)
    {
        #pragma unroll
        for (int it = 0; it < 2; it++)
            #pragma unroll
            for (int nt = 0; nt < 2; nt++) {
                int n = wv * 32 + nt * 16 + (l & 15);
                float bb = bq[n];
                #pragma unroll
                for (int r = 0; r < 4; r++) {
                    int i = it * 16 + (l >> 4) * 4 + r;
                    q16[(size_t)(r0 + i) * 128 + n] =
                            (f16)fast_tanh(acc[it][nt][r] + bb);
                }
            }
    }
    __syncthreads();                             // wl1 reads done
    STAGEW(2);
    __syncthreads();

    ZACC();
    GEMMCORE(hsl);                               // k
    __syncthreads();                             // wl2 reads done; xs free
    f16* ts = (f16*)xs;
    {
        #pragma unroll
        for (int it = 0; it < 2; it++)
            #pragma unroll
            for (int nt = 0; nt < 2; nt++) {
                int n = wv * 32 + nt * 16 + (l & 15);
                float bb = bk[n];
                #pragma unroll
                for (int r = 0; r < 4; r++) {
                    int i = it * 16 + (l >> 4) * 4 + r;
                    ts[i * 128 + n] = (f16)fast_tanh(acc[it][nt][r] + bb);
                }
            }
    }
    STAGEW(3);
    __syncthreads();                             // ts + wl3 ready
    {   // kimg vector writes from ts
        #pragma unroll
        for (int half = 0; half < 2; half++) {
            int row = (t >> 4) + half * 16;
            int seg = t & 15;
            int jg = r0 + row;
            int chunk = ((jg >> 10) << 3) + ((jg & 1023) >> 7);
            int jp = jg & 127;
            char* dst = kimg + (size_t)chunk * 32768 + jp * 256
                      + ((seg * 16) ^ ((jp & 7) << 4));
            *(f16x8*)dst = *(const f16x8*)&ts[row * 128 + seg * 8];
        }
    }
    ZACC();
    GEMMCORE(hsl);                               // v
    {
        #pragma unroll
        for (int it = 0; it < 2; it++)
            #pragma unroll
            for (int nt = 0; nt < 2; nt++) {
                int d = wv * 32 + nt * 16 + (l & 15);
                float bb = bv[d];
                f16x4 h;
                #pragma unroll
                for (int r = 0; r < 4; r++)
                    h[r] = (f16)fast_tanh(acc[it][nt][r] + bb);
                int jb = r0 + it * 16 + ((l >> 4) << 2);
                int chunk = ((jb >> 10) << 3) + ((jb & 1023) >> 7);
                char* dst = vimg + (size_t)chunk * 32768 + d * 256
                          + ((2 * (jb & 127)) ^ ((d & 7) << 4));
                *(f16x4*)dst = h;
            }
    }
}

// ---------------------------------------------------------------------------
// attn_all: block = (b = blk&7 XCD-pinned, 32 Q rows), 512 thr / 8 waves.
// ---------------------------------------------------------------------------
#define ISSUE32(src, bi) do { const char* _g = (src) + t * 16; \
    char* _d = BUF + (bi) * 32768 + t * 16; \
    _Pragma("unroll") for (int _i = 0; _i < 4; _i++) \
        __builtin_amdgcn_global_load_lds( \
            (const __attribute__((address_space(1))) unsigned*)(_g + _i * 8192), \
            (__attribute__((address_space(3))) unsigned*)(_d + _i * 8192), 16, 0, 0); \
} while (0)

__global__ __launch_bounds__(512) void attn_all(
        const f16* __restrict__ q16, const char* __restrict__ kimg,
        const char* __restrict__ pekimg, const char* __restrict__ vimg,
        const char* __restrict__ pevimg, const float* __restrict__ PEK,
        const float* __restrict__ PEV, const f16* __restrict__ w1t,
        const float* __restrict__ b1, float* __restrict__ out) {
    extern __shared__ __align__(16) char sm6[];
    f16*   S   = (f16*)sm6;                              // 74240 B
    char*  BUF = sm6 + 74240;                            // 2 x 32768
    f16*   QB  = (f16*)(sm6 + 74240 + 65536);            // 8448 B
    float* LR  = (float*)(sm6 + 74240 + 65536 + 8448);   // 128 B

    const int t = threadIdx.x, wv = t >> 6, l = t & 63;
    const int lr = l & 15, lg = l >> 4;
    const int b = blockIdx.x & 7;
    const int i0 = (blockIdx.x >> 3) << 5;
    const int it16 = (wv & 1) << 4;
    const int jsub = wv >> 1;

    // Q fragments for this wave's i-half (B operand of QK)
    f16x8 qf[4];
    {
        const f16* qb = q16 + (size_t)(b * TT + i0 + it16 + lr) * 128 + lg * 8;
        #pragma unroll
        for (int c = 0; c < 4; c++) qf[c] = *(const f16x8*)(qb + c * 32);
    }

    const char* kbase = kimg + (size_t)b * 8 * 32768;
    const char* vbase = vimg + (size_t)b * 8 * 32768;

    // ---------------- Phase 1: extended QK -> S ----------------
    ISSUE32(kbase, 0);
    for (int ch = 0; ch < 9; ++ch) {
        asm volatile("s_waitcnt vmcnt(0)" ::: "memory");
        __builtin_amdgcn_s_barrier();
        __builtin_amdgcn_sched_barrier(0);
        if (ch < 8)
            ISSUE32(ch < 7 ? kbase + (size_t)(ch + 1) * 32768 : pekimg, (ch + 1) & 1);
        const char* kb = BUF + (ch & 1) * 32768;
        #pragma unroll
        for (int jt = 0; jt < 2; jt++) {
            const int jp = jsub * 32 + jt * 16 + lr;
            f32x4 acc = {0.f, 0.f, 0.f, 0.f};
            #pragma unroll
            for (int c = 0; c < 4; c++) {
                f16x8 kf = *(const f16x8*)(kb + jp * 256
                            + ((c * 64 + lg * 16) ^ ((jp & 7) << 4)));
                acc = __builtin_amdgcn_mfma_f32_16x16x32_f16(kf, qf[c], acc, 0, 0, 0);
            }
            f16x4 h = {(f16)acc[0], (f16)acc[1], (f16)acc[2], (f16)acc[3]};
            *(f16x4*)&S[(it16 + lr) * SJH + ch * 128 + jsub * 32 + jt * 16 + lg * 4] = h;
        }
    }
    asm volatile("s_waitcnt lgkmcnt(0)" ::: "memory");
    __builtin_amdgcn_s_barrier();
    __builtin_amdgcn_sched_barrier(0);
    ISSUE32(vbase, 0);                                   // prefetch V0 under phase 2

    // ---------------- Phase 2: softmax + buckets (row = t>>4) ----------------
    {
        const int row = t >> 4, l16 = t & 15;
        const int ig = i0 + row;
        f16* srow = S + row * SJH;
        f16* qrow = QB + row * 132;

        float qp;   // qpe[row][128] = Q[row] . pe_key[128]
        {
            const f16* qr = q16 + (size_t)(b * TT + ig) * 128 + l16 * 8;
            const float* pr = PEK + 128 * 128 + l16 * 8;
            f16x8 qv = *(const f16x8*)qr;
            float s = 0.f;
            #pragma unroll
            for (int e = 0; e < 8; e++) s += (float)qv[e] * pr[e];
            #pragma unroll
            for (int off = 8; off; off >>= 1) s += __shfl_xor(s, off, 64);
            qp = s;
        }
        for (int mm = l16; mm < 128; mm += 16) {   // qpe S->QB, zero buckets
            qrow[mm] = srow[1024 + mm];
            srow[1024 + mm] = (f16)0.f;
        }
        if (l16 == 0) qrow[128] = (f16)qp;
        const float qlo = (float)qrow[0], qhi = qp;

        float lmax = -3.0e38f;
        #pragma unroll
        for (int kk = 0; kk < 8; kk++) {
            int j0 = kk * 128 + l16 * 8;
            f16x8 sv = *(const f16x8*)(srow + j0);
            #pragma unroll
            for (int e = 0; e < 8; e++) {
                int idd = 64 + j0 + e - ig;
                float qv = (idd <= 0) ? qlo : (idd >= 128 ? qhi : (float)qrow[idd]);
                lmax = fmaxf(lmax, (float)sv[e] + qv);
            }
        }
        #pragma unroll
        for (int off = 8; off; off >>= 1) lmax = fmaxf(lmax, __shfl_xor(lmax, off, 64));

        float lsum = 0.f, s0 = 0.f, s1 = 0.f;
        #pragma unroll
        for (int kk = 0; kk < 8; kk++) {
            int j0 = kk * 128 + l16 * 8;
            f16x8 sv = *(const f16x8*)(srow + j0);
            f16x8 pv;
            #pragma unroll
            for (int e = 0; e < 8; e++) {
                int idd = 64 + j0 + e - ig;
                float qv = (idd <= 0) ? qlo : (idd >= 128 ? qhi : (float)qrow[idd]);
                float p = __expf((float)sv[e] + qv - lmax);
                pv[e] = (f16)p;
                lsum += p;
                if (idd <= 0)        s0 += p;
                else if (idd >= 128) s1 += p;
                else                 srow[1024 + idd] = (f16)p;   // band bucket
            }
            *(f16x8*)(srow + j0) = pv;          // unnormalized P
        }
        #pragma unroll
        for (int off = 8; off; off >>= 1) {
            lsum += __shfl_xor(lsum, off, 64);
            s0   += __shfl_xor(s0,   off, 64);
            s1   += __shfl_xor(s1,   off, 64);
        }
        if (l16 == 0) {
            srow[1024] = (f16)s0;
            srow[1152] = (f16)s1;
            LR[row] = lsum;
        }
    }
    asm volatile("s_waitcnt lgkmcnt(0)" ::: "memory");
    __builtin_amdgcn_s_barrier();
    __builtin_amdgcn_sched_barrier(0);

    // ---------------- Phase 3: C^T = V'^T . P'^T ----------------
    f32x4 cacc[2] = {};
    for (int ch = 0; ch < 9; ++ch) {
        asm volatile("s_waitcnt vmcnt(0)" ::: "memory");
        __builtin_amdgcn_s_barrier();
        __builtin_amdgcn_sched_barrier(0);
        if (ch < 8)
            ISSUE32(ch < 7 ? vbase + (size_t)(ch + 1) * 32768 : pevimg, (ch + 1) & 1);
        const char* vb = BUF + (ch & 1) * 32768;
        const int dp = wv * 16 + lr;
        #pragma unroll
        for (int c2 = 0; c2 < 4; c2++) {
            f16x8 vf = *(const f16x8*)(vb + dp * 256
                        + ((c2 * 64 + lg * 16) ^ ((dp & 7) << 4)));
            #pragma unroll
            for (int i2 = 0; i2 < 2; i2++) {
                f16x8 pf = *(const f16x8*)&S[(i2 * 16 + lr) * SJH
                            + ch * 128 + c2 * 32 + lg * 8];
                cacc[i2] = __builtin_amdgcn_mfma_f32_16x16x32_f16(vf, pf, cacc[i2], 0, 0, 0);
            }
        }
    }

    // ---- epilogue: + w[128]*pe_value[128], normalize -> c-tile in LDS ----
    float w128[2], rden[2];
    #pragma unroll
    for (int i2 = 0; i2 < 2; i2++) {
        int irow = i2 * 16 + lr;
        w128[i2] = (float)S[irow * SJH + 1152];
        rden[i2] = 1.f / LR[irow];
    }
    __syncthreads();                                     // S/LR reads done; BUF free
    char* cl = (char*)S;                                 // c-tile [i][d] swizzled
    {
        const float* pvr = PEV + 128 * 128;
        #pragma unroll
        for (int i2 = 0; i2 < 2; i2++) {
            int i = i2 * 16 + lr;
            #pragma unroll
            for (int r = 0; r < 4; r++) {
                int d = wv * 16 + lg * 4 + r;
                float cv = (cacc[i2][r] + w128[i2] * pvr[d]) * rden[i2];
                int a = i * 256 + 2 * d;
                *(f16*)(cl + (a ^ ((i & 7) << 4))) = (f16)cv;
            }
        }
    }
    char* wl4 = BUF;                                     // stage W1^T
    {
        const char* src = (const char*)w1t;
        #pragma unroll
        for (int i = 0; i < 4; i++) {
            int a = t * 64 + i * 16;
            uint4 dta = *(const uint4*)(src + a);
            *(uint4*)(wl4 + (a ^ (((a >> 8) & 7) << 4))) = dta;
        }
    }
    __syncthreads();

    // ---- tail GEMM: out = relu(c @ W1 + b1), fp32 ----
    f32x4 oacc[2] = {};
    #pragma unroll
    for (int c = 0; c < 4; c++) {
        f16x8 af[2], bf;
        #pragma unroll
        for (int i2 = 0; i2 < 2; i2++) {
            int row = i2 * 16 + lr;
            int a = (row << 8) + (c << 6) + (lg << 4);
            af[i2] = *(const f16x8*)(cl + (a ^ ((row & 7) << 4)));
        }
        {
            int n = wv * 16 + lr;
            int a = (n << 8) + (c << 6) + (lg << 4);
            bf = *(const f16x8*)(wl4 + (a ^ ((n & 7) << 4)));
        }
        #pragma unroll
        for (int i2 = 0; i2 < 2; i2++)
            oacc[i2] = __builtin_amdgcn_mfma_f32_16x16x32_f16(af[i2], bf, oacc[i2], 0, 0, 0);
    }
    {
        int n = wv * 16 + lr;
        float bb = b1[n];
        #pragma unroll
        for (int i2 = 0; i2 < 2; i2++) {
            #pragma unroll
            for (int r = 0; r < 4; r++) {
                int i = i2 * 16 + lg * 4 + r;
                out[(size_t)(b * TT + i0 + i) * DD + n] = fmaxf(oacc[i2][r] + bb, 0.f);
            }
        }
    }
}

// ---------------------------------------------------------------------------

extern "C" void kernel_launch(void* const* d_in, const int* in_sizes, int n_in,
                              void* d_out, int out_size, void* d_ws, size_t ws_size,
                              hipStream_t stream) {
    const float* x   = (const float*)d_in[0];
    const float* W0  = (const float*)d_in[1];
    const float* b0  = (const float*)d_in[2];
    const float* Wq  = (const float*)d_in[3];
    const float* bq  = (const float*)d_in[4];
    const float* Wk  = (const float*)d_in[5];
    const float* bk  = (const float*)d_in[6];
    const float* Wv  = (const float*)d_in[7];
    const float* bv  = (const float*)d_in[8];
    const float* W1  = (const float*)d_in[9];
    const float* b1  = (const float*)d_in[10];
    const float* pek = (const float*)d_in[11];
    const float* pev = (const float*)d_in[12];
    float* out = (float*)d_out;

    const size_t NTD = (size_t)NB * TT * DD;   // 1,048,576 elements
    f16* q16 = (f16*)d_ws;                     // 2 MB
    f16* wt  = q16 + NTD;                      // 5 * 16384 f16
    char* kimg   = (char*)(wt + 5 * 16384);    // 64 x 32KB = 2 MB
    char* vimg   = kimg + (size_t)64 * 32768;  // 2 MB
    char* pekimg = vimg + (size_t)64 * 32768;  // 32 KB
    char* pevimg = pekimg + 32768;             // 32 KB

    const int SMEM_ATTN = 74240 + 65536 + 8448 + 128;   // 148,352 B
    hipFuncSetAttribute(reinterpret_cast<const void*>(attn_all),
                        hipFuncAttributeMaxDynamicSharedMemorySize, SMEM_ATTN);

    hipLaunchKernelGGL(prep_w, dim3(5), dim3(256), 0, stream,
                       W0, Wq, Wk, Wv, W1, wt);
    hipLaunchKernelGGL(fused_qkv, dim3(258), dim3(256), 0, stream,
                       x, wt, b0, bq, bk, bv, pek, pev,
                       q16, kimg, vimg, pekimg, pevimg);
    hipLaunchKernelGGL(attn_all, dim3(256), dim3(512), SMEM_ATTN, stream,
                       q16, kimg, pekimg, vimg, pevimg, pek, pev,
                       wt + 4 * 16384, b1, out);
}

// Round 7
// 53.835 us; speedup vs baseline: 7.4481x; 1.0493x over previous
//
#include <hip/hip_runtime.h>

// ---------------------------------------------------------------------------
// SelfAttentionRPR: B=8, T=1024, D=128, K=64, DEPTH=1, fp32 in/out.
// R7: 3 kernels.
//  prep_w:    pre-swizzled W^T f16 images (32KB each) for global_load_lds.
//  fused_qkv: fc0+Q/K/V chain, W staged async one phase ahead (2 wl buffers);
//             K/V written as pre-swizzled 16KB attention chunks.
//  attn_all:  unified 36-chunk stream (18 K' + 18 V'), 16KB chunks, 4 LDS
//             buffers, depth-3 counted vmcnt(4); W1^T prefetched into freed
//             buffers at the tail; phase-2 operands preloaded to registers
//             (no vm ops between chunk issues). Tail GEMM fused.
// K chunk: 64 j-rows x 256B, byte^=((j&7)<<4).  V chunk: 128 d-rows x 128B
// (64 j-cols), byte^=((d&7)<<4).  W image: [n][k] 256B rows, byte^=((n&7)<<4),
// stored pre-swizzled so linear DMA lands swizzled.
// ---------------------------------------------------------------------------

#define TT 1024
#define DD 128
#define NB 8
#define SJH 1160         // S row stride (f16)

typedef _Float16 f16;
typedef __attribute__((ext_vector_type(8))) _Float16 f16x8;
typedef __attribute__((ext_vector_type(4))) _Float16 f16x4;
typedef __attribute__((ext_vector_type(4))) float f32x4;

static __device__ inline float fast_tanh(float x) {
    float xc = fminf(fmaxf(x, -12.f), 12.f);
    float e = __expf(2.f * xc);
    return (e - 1.f) / (e + 1.f);
}

#define GLDS(gp, lp) __builtin_amdgcn_global_load_lds( \
    (const __attribute__((address_space(1))) unsigned*)(gp), \
    (__attribute__((address_space(3))) unsigned*)(lp), 16, 0, 0)

// ---------------------------------------------------------------------------
// prep_w: W^T f16 pre-swizzled images. img[y] = W^T[y ^ s(y)], s(y)=((y>>8)&7)<<4
// so that linear DMA into LDS yields wl[a^s(a)] = W^T[a].
// ---------------------------------------------------------------------------
__global__ __launch_bounds__(256) void prep_w(
        const float* __restrict__ W0, const float* __restrict__ Wq,
        const float* __restrict__ Wk, const float* __restrict__ Wv,
        const float* __restrict__ W1, char* __restrict__ wimg) {
    const int blk = blockIdx.x, t = threadIdx.x;
    const float* W = blk == 0 ? W0 : blk == 1 ? Wq : blk == 2 ? Wk
                   : blk == 3 ? Wv : W1;
    char* o = wimg + (size_t)blk * 32768;
    for (int it = 0; it < 64; it++) {
        int idx = t + 256 * it;                  // coalesced loads (n-major)
        int k = idx >> 7, n = idx & 127;
        int a = n * 256 + 2 * k;
        *(f16*)(o + (a ^ ((n & 7) << 4))) = (f16)W[k * 128 + n];
    }
}

// ---------------------------------------------------------------------------
#define ZACC() do { _Pragma("unroll") for (int _i = 0; _i < 2; _i++) \
    _Pragma("unroll") for (int _j = 0; _j < 2; _j++) \
        acc[_i][_j] = (f32x4){0.f, 0.f, 0.f, 0.f}; } while (0)

#define GEMMCORE(SRC, WL) do { \
    _Pragma("unroll") for (int _c = 0; _c < 4; _c++) { \
        f16x8 _af[2], _bf[2]; \
        _Pragma("unroll") for (int _it = 0; _it < 2; _it++) { \
            int _row = _it * 16 + (l & 15); \
            int _a = (_row << 8) + (_c << 6) + ((l >> 4) << 4); \
            _af[_it] = *(const f16x8*)((SRC) + (_a ^ ((_row & 7) << 4))); } \
        _Pragma("unroll") for (int _nt = 0; _nt < 2; _nt++) { \
            int _n = wv * 32 + _nt * 16 + (l & 15); \
            int _a = (_n << 8) + (_c << 6) + ((l >> 4) << 4); \
            _bf[_nt] = *(const f16x8*)((WL) + (_a ^ ((_n & 7) << 4))); } \
        _Pragma("unroll") for (int _it = 0; _it < 2; _it++) \
        _Pragma("unroll") for (int _nt = 0; _nt < 2; _nt++) \
            acc[_it][_nt] = __builtin_amdgcn_mfma_f32_16x16x32_f16( \
                    _af[_it], _bf[_nt], acc[_it][_nt], 0, 0, 0); } } while (0)

#define ISSUEW(wi, dst) do { \
    const char* _g = wimg + (size_t)(wi) * 32768 + t * 16; \
    char* _d = (dst) + t * 16; \
    _Pragma("unroll") for (int _i = 0; _i < 8; _i++) \
        GLDS(_g + _i * 4096, _d + _i * 4096); \
} while (0)

#define QKVBAR() do { \
    asm volatile("s_waitcnt vmcnt(0) lgkmcnt(0)" ::: "memory"); \
    __builtin_amdgcn_s_barrier(); \
    __builtin_amdgcn_sched_barrier(0); \
} while (0)

// fused_qkv: blocks 0..255 = 32-row GEMM chain; 256/257 = pe image builders.
__global__ __launch_bounds__(256) void fused_qkv(
        const float* __restrict__ x, const char* __restrict__ wimg,
        const float* __restrict__ b0, const float* __restrict__ bq,
        const float* __restrict__ bk, const float* __restrict__ bv,
        const float* __restrict__ PEK, const float* __restrict__ PEV,
        f16* __restrict__ q16, char* __restrict__ kimg,
        char* __restrict__ vimg, char* __restrict__ pekimg,
        char* __restrict__ pevimg) {
    extern __shared__ __align__(16) char smq[];
    char* xs  = smq;            // 8KB  x-tile (later ts)
    char* hsl = smq + 8192;     // 8KB  hs-tile
    char* wA  = smq + 16384;    // 32KB W buffer A
    char* wB  = smq + 49152;    // 32KB W buffer B
    const int t = threadIdx.x, wv = t >> 6, l = t & 63;
    const int blk = blockIdx.x;

    if (blk >= 256) {                            // pe image builders
        if (blk == 256) {
            for (int it = 0; it < 64; it++) {
                int idx = t + 256 * it;
                int m = idx >> 7, d = idx & 127;
                *(f16*)(pekimg + (m >> 6) * 16384 + (m & 63) * 256
                        + ((2 * d) ^ ((m & 7) << 4))) = (f16)PEK[m * 128 + d];
            }
        } else {
            for (int it = 0; it < 64; it++) {
                int idx = t + 256 * it;
                int m = idx >> 7, d = idx & 127;
                *(f16*)(pevimg + (m >> 6) * 16384 + d * 128
                        + ((2 * (m & 63)) ^ ((d & 7) << 4))) = (f16)PEV[m * 128 + d];
            }
        }
        return;
    }

    const int r0 = blk * 32;
    ISSUEW(0, wA);
    {   // stage x (fp32 -> f16, swizzled)
        const float* X = x + (size_t)r0 * 128;
        #pragma unroll
        for (int i = 0; i < 2; i++) {
            f32x4 a0 = *(const f32x4*)(X + t * 16 + i * 8);
            f32x4 a1 = *(const f32x4*)(X + t * 16 + i * 8 + 4);
            f16x8 h;
            h[0]=(f16)a0[0]; h[1]=(f16)a0[1]; h[2]=(f16)a0[2]; h[3]=(f16)a0[3];
            h[4]=(f16)a1[0]; h[5]=(f16)a1[1]; h[6]=(f16)a1[2]; h[7]=(f16)a1[3];
            int a = t * 32 + i * 16;
            *(f16x8*)(xs + (a ^ (((a >> 8) & 7) << 4))) = h;
        }
    }
    QKVBAR();

    f32x4 acc[2][2];
    ISSUEW(1, wB);
    ZACC();
    GEMMCORE(xs, wA);                            // hs = relu(x@W0+b0)
    {
        #pragma unroll
        for (int it = 0; it < 2; it++)
            #pragma unroll
            for (int nt = 0; nt < 2; nt++) {
                int n = wv * 32 + nt * 16 + (l & 15);
                float bb = b0[n];
                #pragma unroll
                for (int r = 0; r < 4; r++) {
                    int i = it * 16 + (l >> 4) * 4 + r;
                    float v = fmaxf(acc[it][nt][r] + bb, 0.f);
                    int a = i * 256 + 2 * n;
                    *(f16*)(hsl + (a ^ ((i & 7) << 4))) = (f16)v;
                }
            }
    }
    QKVBAR();

    ISSUEW(2, wA);
    ZACC();
    GEMMCORE(hsl, wB);                           // q = tanh(hs@Wq+bq)
    {
        #pragma unroll
        for (int it = 0; it < 2; it++)
            #pragma unroll
            for (int nt = 0; nt < 2; nt++) {
                int n = wv * 32 + nt * 16 + (l & 15);
                float bb = bq[n];
                #pragma unroll
                for (int r = 0; r < 4; r++) {
                    int i = it * 16 + (l >> 4) * 4 + r;
                    q16[(size_t)(r0 + i) * 128 + n] =
                            (f16)fast_tanh(acc[it][nt][r] + bb);
                }
            }
    }
    QKVBAR();

    ISSUEW(3, wB);
    ZACC();
    GEMMCORE(hsl, wA);                           // k = tanh(hs@Wk+bk) -> ts
    f16* ts = (f16*)xs;
    {
        #pragma unroll
        for (int it = 0; it < 2; it++)
            #pragma unroll
            for (int nt = 0; nt < 2; nt++) {
                int n = wv * 32 + nt * 16 + (l & 15);
                float bb = bk[n];
                #pragma unroll
                for (int r = 0; r < 4; r++) {
                    int i = it * 16 + (l >> 4) * 4 + r;
                    ts[i * 128 + n] = (f16)fast_tanh(acc[it][nt][r] + bb);
                }
            }
    }
    QKVBAR();

    {   // kimg writes from ts (16KB chunks: 64 rows x 256B)
        #pragma unroll
        for (int half = 0; half < 2; half++) {
            int row = (t >> 4) + half * 16;
            int seg = t & 15;
            int jg = r0 + row;
            int chunk = ((jg >> 10) << 4) + ((jg & 1023) >> 6);
            int jp = jg & 63;
            char* dst = kimg + (size_t)chunk * 16384 + jp * 256
                      + ((seg * 16) ^ ((jp & 7) << 4));
            *(f16x8*)dst = *(const f16x8*)&ts[row * 128 + seg * 8];
        }
    }
    ZACC();
    GEMMCORE(hsl, wB);                           // v = tanh(hs@Wv+bv)
    {
        #pragma unroll
        for (int it = 0; it < 2; it++)
            #pragma unroll
            for (int nt = 0; nt < 2; nt++) {
                int d = wv * 32 + nt * 16 + (l & 15);
                float bb = bv[d];
                f16x4 h;
                #pragma unroll
                for (int r = 0; r < 4; r++)
                    h[r] = (f16)fast_tanh(acc[it][nt][r] + bb);
                int jb = r0 + it * 16 + ((l >> 4) << 2);
                int chunk = ((jb >> 10) << 4) + ((jb & 1023) >> 6);
                char* dst = vimg + (size_t)chunk * 16384 + d * 128
                          + ((2 * (jb & 63)) ^ ((d & 7) << 4));
                *(f16x4*)dst = h;
            }
    }
}

// ---------------------------------------------------------------------------
// attn_all: block = (b = blk&7 XCD-pinned, 32 Q rows), 512 thr / 8 waves.
// Unified chunk stream 0..35 (18 K'+pek, 18 V'+pev); buffer = chunkidx & 3.
// ---------------------------------------------------------------------------
#define ISSUE16(src, bi) do { const char* _g = (src) + t * 16; \
    char* _d = BUF + (size_t)(bi) * 16384 + t * 16; \
    GLDS(_g, _d); \
    GLDS(_g + 8192, _d + 8192); \
} while (0)

__global__ __launch_bounds__(512) void attn_all(
        const f16* __restrict__ q16, const char* __restrict__ kimg,
        const char* __restrict__ pekimg, const char* __restrict__ vimg,
        const char* __restrict__ pevimg, const float* __restrict__ PEK,
        const float* __restrict__ PEV, const char* __restrict__ w1img,
        const float* __restrict__ b1, float* __restrict__ out) {
    extern __shared__ __align__(16) char sm7[];
    f16*   S   = (f16*)sm7;                              // 74240 B
    char*  BUF = sm7 + 74240;                            // 4 x 16384
    f16*   QB  = (f16*)(sm7 + 139776);                   // 8448 B
    float* LR  = (float*)(sm7 + 148224);                 // 128 B

    const int t = threadIdx.x, wv = t >> 6, l = t & 63;
    const int lr = l & 15, lg = l >> 4;
    const int b = blockIdx.x & 7;
    const int i0 = (blockIdx.x >> 3) << 5;
    const int it16 = (wv & 1) << 4;
    const int jsub = wv >> 1;

    // ---- register preloads (ALL global reads happen before chunk issues) ----
    f16x8 qf[4];
    {
        const f16* qb = q16 + (size_t)(b * TT + i0 + it16 + lr) * 128 + lg * 8;
        #pragma unroll
        for (int c = 0; c < 4; c++) qf[c] = *(const f16x8*)(qb + c * 32);
    }
    const int row2 = t >> 4, l16 = t & 15;
    f16x8 qpv = *(const f16x8*)(q16 + (size_t)(b * TT + i0 + row2) * 128 + l16 * 8);
    f32x4 pkv0 = *(const f32x4*)(PEK + 128 * 128 + l16 * 8);
    f32x4 pkv1 = *(const f32x4*)(PEK + 128 * 128 + l16 * 8 + 4);
    f32x4 pvr4 = *(const f32x4*)(PEV + 128 * 128 + wv * 16 + lg * 4);
    const float bb1 = b1[wv * 16 + lr];

    const char* kbase = kimg + (size_t)b * 16 * 16384;
    const char* vbase = vimg + (size_t)b * 16 * 16384;

    // prologue: chunks 0,1,2
    ISSUE16(kbase, 0);
    ISSUE16(kbase + 16384, 1);
    ISSUE16(kbase + 2 * 16384, 2);

    // ---------------- Phase 1: extended QK -> S ----------------
    for (int ch = 0; ch < 18; ch++) {
        asm volatile("s_waitcnt vmcnt(4)" ::: "memory");
        __builtin_amdgcn_s_barrier();
        __builtin_amdgcn_sched_barrier(0);
        {
            int ci = ch + 3;                       // 3..20 (>=18 -> V prefetch)
            const char* src = ci < 16 ? kbase + (size_t)ci * 16384
                            : (ci < 18 ? pekimg + (size_t)(ci - 16) * 16384
                                       : vbase + (size_t)(ci - 18) * 16384);
            ISSUE16(src, ci & 3);
        }
        const char* kb = BUF + (size_t)(ch & 3) * 16384;
        const int jp = jsub * 16 + lr;
        f32x4 acc = {0.f, 0.f, 0.f, 0.f};
        #pragma unroll
        for (int c = 0; c < 4; c++) {
            f16x8 kf = *(const f16x8*)(kb + jp * 256
                        + ((c * 64 + lg * 16) ^ ((jp & 7) << 4)));
            acc = __builtin_amdgcn_mfma_f32_16x16x32_f16(kf, qf[c], acc, 0, 0, 0);
        }
        f16x4 h = {(f16)acc[0], (f16)acc[1], (f16)acc[2], (f16)acc[3]};
        *(f16x4*)&S[(it16 + lr) * SJH + ch * 64 + jsub * 16 + lg * 4] = h;
    }
    asm volatile("s_waitcnt lgkmcnt(0)" ::: "memory");
    __builtin_amdgcn_s_barrier();
    __builtin_amdgcn_sched_barrier(0);

    // ---------------- Phase 2: softmax + buckets (row = t>>4) ----------------
    {
        const int ig = i0 + row2;
        f16* srow = S + row2 * SJH;
        f16* qrow = QB + row2 * 132;

        float qp;   // qpe[row][128] = Q[row] . pe_key[128]  (registers only)
        {
            float s = 0.f;
            #pragma unroll
            for (int e = 0; e < 4; e++) s += (float)qpv[e] * pkv0[e];
            #pragma unroll
            for (int e = 0; e < 4; e++) s += (float)qpv[e + 4] * pkv1[e];
            #pragma unroll
            for (int off = 8; off; off >>= 1) s += __shfl_xor(s, off, 64);
            qp = s;
        }
        for (int mm = l16; mm < 128; mm += 16) {   // qpe S->QB, zero buckets
            qrow[mm] = srow[1024 + mm];
            srow[1024 + mm] = (f16)0.f;
        }
        if (l16 == 0) qrow[128] = (f16)qp;
        const float qlo = (float)qrow[0], qhi = qp;

        float lmax = -3.0e38f;
        #pragma unroll
        for (int kk = 0; kk < 8; kk++) {
            int j0 = kk * 128 + l16 * 8;
            f16x8 sv = *(const f16x8*)(srow + j0);
            #pragma unroll
            for (int e = 0; e < 8; e++) {
                int idd = 64 + j0 + e - ig;
                float qv = (idd <= 0) ? qlo : (idd >= 128 ? qhi : (float)qrow[idd]);
                lmax = fmaxf(lmax, (float)sv[e] + qv);
            }
        }
        #pragma unroll
        for (int off = 8; off; off >>= 1) lmax = fmaxf(lmax, __shfl_xor(lmax, off, 64));

        float lsum = 0.f, s0 = 0.f, s1 = 0.f;
        #pragma unroll
        for (int kk = 0; kk < 8; kk++) {
            int j0 = kk * 128 + l16 * 8;
            f16x8 sv = *(const f16x8*)(srow + j0);
            f16x8 pv;
            #pragma unroll
            for (int e = 0; e < 8; e++) {
                int idd = 64 + j0 + e - ig;
                float qv = (idd <= 0) ? qlo : (idd >= 128 ? qhi : (float)qrow[idd]);
                float p = __expf((float)sv[e] + qv - lmax);
                pv[e] = (f16)p;
                lsum += p;
                if (idd <= 0)        s0 += p;
                else if (idd >= 128) s1 += p;
                else                 srow[1024 + idd] = (f16)p;   // band bucket
            }
            *(f16x8*)(srow + j0) = pv;          // unnormalized P
        }
        #pragma unroll
        for (int off = 8; off; off >>= 1) {
            lsum += __shfl_xor(lsum, off, 64);
            s0   += __shfl_xor(s0,   off, 64);
            s1   += __shfl_xor(s1,   off, 64);
        }
        if (l16 == 0) {
            srow[1024] = (f16)s0;
            srow[1152] = (f16)s1;
            LR[row2] = lsum;
        }
    }
    asm volatile("s_waitcnt lgkmcnt(0)" ::: "memory");
    __builtin_amdgcn_s_barrier();
    __builtin_amdgcn_sched_barrier(0);

    // ---------------- Phase 3: C^T = V'^T . P'^T ----------------
    f32x4 cacc[2] = {};
    for (int ch = 0; ch < 18; ch++) {
        if (ch <= 15)      asm volatile("s_waitcnt vmcnt(4)" ::: "memory");
        else if (ch == 16) asm volatile("s_waitcnt vmcnt(2)" ::: "memory");
        else               asm volatile("s_waitcnt vmcnt(0)" ::: "memory");
        __builtin_amdgcn_s_barrier();
        __builtin_amdgcn_sched_barrier(0);
        if (ch < 15) {
            int ci = ch + 3;                      // local 3..17
            const char* src = ci < 16 ? vbase + (size_t)ci * 16384
                                      : pevimg + (size_t)(ci - 16) * 16384;
            ISSUE16(src, (ci + 2) & 3);
        } else if (ch == 17) {
            // prefetch W1^T image into freed buffers 0..1 (32KB linear)
            const char* _g = w1img + t * 16;
            char* _d = BUF + t * 16;
            #pragma unroll
            for (int _i = 0; _i < 4; _i++)
                GLDS(_g + _i * 8192, _d + _i * 8192);
        }
        const char* vb = BUF + (size_t)((ch + 2) & 3) * 16384;
        const int dp = wv * 16 + lr;
        #pragma unroll
        for (int c2 = 0; c2 < 2; c2++) {
            f16x8 vf = *(const f16x8*)(vb + dp * 128
                        + ((c2 * 64 + lg * 16) ^ ((dp & 7) << 4)));
            #pragma unroll
            for (int i2 = 0; i2 < 2; i2++) {
                f16x8 pf = *(const f16x8*)&S[(i2 * 16 + lr) * SJH
                            + ch * 64 + c2 * 32 + lg * 8];
                cacc[i2] = __builtin_amdgcn_mfma_f32_16x16x32_f16(vf, pf, cacc[i2], 0, 0, 0);
            }
        }
    }

    // ---- epilogue: + w[128]*pe_value[128], normalize -> c-tile in LDS ----
    float w128[2], rden[2];
    #pragma unroll
    for (int i2 = 0; i2 < 2; i2++) {
        int irow = i2 * 16 + lr;
        w128[i2] = (float)S[irow * SJH + 1152];
        rden[i2] = 1.f / LR[irow];
    }
    asm volatile("s_waitcnt lgkmcnt(0)" ::: "memory");
    __builtin_amdgcn_s_barrier();                        // all S reads done
    __builtin_amdgcn_sched_barrier(0);
    char* cl = (char*)S;                                 // c-tile [i][d] swizzled
    {
        #pragma unroll
        for (int i2 = 0; i2 < 2; i2++) {
            int i = i2 * 16 + lr;
            #pragma unroll
            for (int r = 0; r < 4; r++) {
                int d = wv * 16 + lg * 4 + r;
                float cv = (cacc[i2][r] + w128[i2] * pvr4[r]) * rden[i2];
                int a = i * 256 + 2 * d;
                *(f16*)(cl + (a ^ ((i & 7) << 4))) = (f16)cv;
            }
        }
    }
    asm volatile("s_waitcnt vmcnt(0) lgkmcnt(0)" ::: "memory");
    __builtin_amdgcn_s_barrier();                        // W1 landed, cl visible
    __builtin_amdgcn_sched_barrier(0);

    // ---- tail GEMM: out = relu(c @ W1 + b1), fp32 ----
    const char* wl4 = BUF;
    f32x4 oacc[2] = {};
    #pragma unroll
    for (int c = 0; c < 4; c++) {
        f16x8 af[2], bf;
        #pragma unroll
        for (int i2 = 0; i2 < 2; i2++) {
            int row = i2 * 16 + lr;
            int a = (row << 8) + (c << 6) + (lg << 4);
            af[i2] = *(const f16x8*)(cl + (a ^ ((row & 7) << 4)));
        }
        {
            int n = wv * 16 + lr;
            int a = (n << 8) + (c << 6) + (lg << 4);
            bf = *(const f16x8*)(wl4 + (a ^ ((n & 7) << 4)));
        }
        #pragma unroll
        for (int i2 = 0; i2 < 2; i2++)
            oacc[i2] = __builtin_amdgcn_mfma_f32_16x16x32_f16(af[i2], bf, oacc[i2], 0, 0, 0);
    }
    {
        int n = wv * 16 + lr;
        #pragma unroll
        for (int i2 = 0; i2 < 2; i2++) {
            #pragma unroll
            for (int r = 0; r < 4; r++) {
                int i = i2 * 16 + lg * 4 + r;
                out[(size_t)(b * TT + i0 + i) * DD + n] = fmaxf(oacc[i2][r] + bb1, 0.f);
            }
        }
    }
}

// ---------------------------------------------------------------------------

extern "C" void kernel_launch(void* const* d_in, const int* in_sizes, int n_in,
                              void* d_out, int out_size, void* d_ws, size_t ws_size,
                              hipStream_t stream) {
    const float* x   = (const float*)d_in[0];
    const float* W0  = (const float*)d_in[1];
    const float* b0  = (const float*)d_in[2];
    const float* Wq  = (const float*)d_in[3];
    const float* bq  = (const float*)d_in[4];
    const float* Wk  = (const float*)d_in[5];
    const float* bk  = (const float*)d_in[6];
    const float* Wv  = (const float*)d_in[7];
    const float* bv  = (const float*)d_in[8];
    const float* W1  = (const float*)d_in[9];
    const float* b1  = (const float*)d_in[10];
    const float* pek = (const float*)d_in[11];
    const float* pev = (const float*)d_in[12];
    float* out = (float*)d_out;

    const size_t NTD = (size_t)NB * TT * DD;   // 1,048,576 elements
    f16* q16 = (f16*)d_ws;                     // 2 MB
    char* wimg   = (char*)(q16 + NTD);         // 5 x 32KB = 160 KB
    char* kimg   = wimg + 5 * 32768;           // 128 x 16KB = 2 MB
    char* vimg   = kimg + (size_t)128 * 16384; // 2 MB
    char* pekimg = vimg + (size_t)128 * 16384; // 32 KB
    char* pevimg = pekimg + 32768;             // 32 KB

    const int SMEM_QKV  = 81920;
    const int SMEM_ATTN = 148352;
    hipFuncSetAttribute(reinterpret_cast<const void*>(fused_qkv),
                        hipFuncAttributeMaxDynamicSharedMemorySize, SMEM_QKV);
    hipFuncSetAttribute(reinterpret_cast<const void*>(attn_all),
                        hipFuncAttributeMaxDynamicSharedMemorySize, SMEM_ATTN);

    hipLaunchKernelGGL(prep_w, dim3(5), dim3(256), 0, stream,
                       W0, Wq, Wk, Wv, W1, wimg);
    hipLaunchKernelGGL(fused_qkv, dim3(258), dim3(256), SMEM_QKV, stream,
                       x, wimg, b0, bq, bk, bv, pek, pev,
                       q16, kimg, vimg, pekimg, pevimg);
    hipLaunchKernelGGL(attn_all, dim3(256), dim3(512), SMEM_ATTN, stream,
                       q16, kimg, pekimg, vimg, pevimg, pek, pev,
                       wimg + 4 * 32768, b1, out);
}

// Round 8
// 51.819 us; speedup vs baseline: 7.7379x; 1.0389x over previous
//
#include <hip/hip_runtime.h>

// ---------------------------------------------------------------------------
// SelfAttentionRPR: B=8, T=1024, D=128, K=64, DEPTH=1, fp32 in/out.
// R8: 3 kernels.
//  prep_w:    vectorized pre-swizzled W^T f16 images (32KB each).
//  fused_qkv: fc0+Q/K/V chain; 3 W LDS buffers with COUNTED vmcnt(8) waits
//             (true cross-barrier W prefetch); block->(batch,slice) remap so
//             writer XCD == attn reader XCD; K/V written as 16KB chunks.
//  attn_all:  unchanged R7 (36-chunk stream, depth-3 vmcnt(4), fused tail).
// ---------------------------------------------------------------------------

#define TT 1024
#define DD 128
#define NB 8
#define SJH 1160         // S row stride (f16)

typedef _Float16 f16;
typedef __attribute__((ext_vector_type(8))) _Float16 f16x8;
typedef __attribute__((ext_vector_type(4))) _Float16 f16x4;
typedef __attribute__((ext_vector_type(4))) float f32x4;

static __device__ inline float fast_tanh(float x) {
    float xc = fminf(fmaxf(x, -12.f), 12.f);
    float e = __expf(2.f * xc);
    return (e - 1.f) / (e + 1.f);
}

#define GLDS(gp, lp) __builtin_amdgcn_global_load_lds( \
    (const __attribute__((address_space(1))) unsigned*)(gp), \
    (__attribute__((address_space(3))) unsigned*)(lp), 16, 0, 0)

// ---------------------------------------------------------------------------
// prep_w: W^T f16 pre-swizzled images. Work item (n, k0): pack W[k0..k0+7][n]
// (per-instruction coalesced: lanes read consecutive n) into one f16x8 store
// at n*256 + ((2*k0) ^ ((n&7)<<4)).
// ---------------------------------------------------------------------------
__global__ __launch_bounds__(256) void prep_w(
        const float* __restrict__ W0, const float* __restrict__ Wq,
        const float* __restrict__ Wk, const float* __restrict__ Wv,
        const float* __restrict__ W1, char* __restrict__ wimg) {
    const int blk = blockIdx.x, t = threadIdx.x;
    const float* W = blk == 0 ? W0 : blk == 1 ? Wq : blk == 2 ? Wk
                   : blk == 3 ? Wv : W1;
    char* o = wimg + (size_t)blk * 32768;
    #pragma unroll
    for (int it = 0; it < 8; it++) {
        int item = t + 256 * it;                 // 2048 items
        int n = item & 127, k0 = (item >> 7) * 8;
        f16x8 h;
        #pragma unroll
        for (int e = 0; e < 8; e++) h[e] = (f16)W[(k0 + e) * 128 + n];
        *(f16x8*)(o + n * 256 + ((2 * k0) ^ ((n & 7) << 4))) = h;
    }
}

// ---------------------------------------------------------------------------
#define ZACC() do { _Pragma("unroll") for (int _i = 0; _i < 2; _i++) \
    _Pragma("unroll") for (int _j = 0; _j < 2; _j++) \
        acc[_i][_j] = (f32x4){0.f, 0.f, 0.f, 0.f}; } while (0)

#define GEMMCORE(SRC, WL) do { \
    _Pragma("unroll") for (int _c = 0; _c < 4; _c++) { \
        f16x8 _af[2], _bf[2]; \
        _Pragma("unroll") for (int _it = 0; _it < 2; _it++) { \
            int _row = _it * 16 + (l & 15); \
            int _a = (_row << 8) + (_c << 6) + ((l >> 4) << 4); \
            _af[_it] = *(const f16x8*)((SRC) + (_a ^ ((_row & 7) << 4))); } \
        _Pragma("unroll") for (int _nt = 0; _nt < 2; _nt++) { \
            int _n = wv * 32 + _nt * 16 + (l & 15); \
            int _a = (_n << 8) + (_c << 6) + ((l >> 4) << 4); \
            _bf[_nt] = *(const f16x8*)((WL) + (_a ^ ((_n & 7) << 4))); } \
        _Pragma("unroll") for (int _it = 0; _it < 2; _it++) \
        _Pragma("unroll") for (int _nt = 0; _nt < 2; _nt++) \
            acc[_it][_nt] = __builtin_amdgcn_mfma_f32_16x16x32_f16( \
                    _af[_it], _bf[_nt], acc[_it][_nt], 0, 0, 0); } } while (0)

#define ISSUEW(wi, dst) do { \
    const char* _g = wimg + (size_t)(wi) * 32768 + t * 16; \
    char* _d = (dst) + t * 16; \
    _Pragma("unroll") for (int _i = 0; _i < 8; _i++) \
        GLDS(_g + _i * 4096, _d + _i * 4096); \
} while (0)

#define WAITBAR(N) do { \
    asm volatile("s_waitcnt vmcnt(" #N ") lgkmcnt(0)" ::: "memory"); \
    __builtin_amdgcn_s_barrier(); \
    __builtin_amdgcn_sched_barrier(0); \
} while (0)

// fused_qkv: blocks 0..255 -> (b = blk&7, slice = blk>>3): rows b*1024+slice*32
// (writer XCD == attn reader XCD).  Blocks 256/257 = pe image builders.
__global__ __launch_bounds__(256) void fused_qkv(
        const float* __restrict__ x, const char* __restrict__ wimg,
        const float* __restrict__ b0, const float* __restrict__ bq,
        const float* __restrict__ bk, const float* __restrict__ bv,
        const float* __restrict__ PEK, const float* __restrict__ PEV,
        f16* __restrict__ q16, char* __restrict__ kimg,
        char* __restrict__ vimg, char* __restrict__ pekimg,
        char* __restrict__ pevimg) {
    extern __shared__ __align__(16) char smq[];
    char* xs  = smq;            // 8KB  x-tile (later ts)
    char* hsl = smq + 8192;     // 8KB  hs-tile
    char* wA  = smq + 16384;    // 32KB
    char* wB  = smq + 49152;    // 32KB
    char* wC  = smq + 81920;    // 32KB
    const int t = threadIdx.x, wv = t >> 6, l = t & 63;
    const int blk = blockIdx.x;

    if (blk >= 256) {                            // pe image builders
        if (blk == 256) {
            for (int it = 0; it < 64; it++) {
                int idx = t + 256 * it;
                int m = idx >> 7, d = idx & 127;
                *(f16*)(pekimg + (m >> 6) * 16384 + (m & 63) * 256
                        + ((2 * d) ^ ((m & 7) << 4))) = (f16)PEK[m * 128 + d];
            }
        } else {
            for (int it = 0; it < 64; it++) {
                int idx = t + 256 * it;
                int m = idx >> 7, d = idx & 127;
                *(f16*)(pevimg + (m >> 6) * 16384 + d * 128
                        + ((2 * (m & 63)) ^ ((d & 7) << 4))) = (f16)PEV[m * 128 + d];
            }
        }
        return;
    }

    const int r0 = (blk & 7) * 1024 + (blk >> 3) * 32;   // XCD-aligned rows
    ISSUEW(0, wA);
    ISSUEW(1, wB);
    {   // stage x (fp32 -> f16, swizzled)
        const float* X = x + (size_t)r0 * 128;
        #pragma unroll
        for (int i = 0; i < 2; i++) {
            f32x4 a0 = *(const f32x4*)(X + t * 16 + i * 8);
            f32x4 a1 = *(const f32x4*)(X + t * 16 + i * 8 + 4);
            f16x8 h;
            h[0]=(f16)a0[0]; h[1]=(f16)a0[1]; h[2]=(f16)a0[2]; h[3]=(f16)a0[3];
            h[4]=(f16)a1[0]; h[5]=(f16)a1[1]; h[6]=(f16)a1[2]; h[7]=(f16)a1[3];
            int a = t * 32 + i * 16;
            *(f16x8*)(xs + (a ^ (((a >> 8) & 7) << 4))) = h;
        }
    }
    WAITBAR(8);                                  // W0 landed; W1 in flight

    f32x4 acc[2][2];
    ZACC();
    GEMMCORE(xs, wA);                            // hs = relu(x@W0+b0)
    {
        #pragma unroll
        for (int it = 0; it < 2; it++)
            #pragma unroll
            for (int nt = 0; nt < 2; nt++) {
                int n = wv * 32 + nt * 16 + (l & 15);
                float bb = b0[n];
                #pragma unroll
                for (int r = 0; r < 4; r++) {
                    int i = it * 16 + (l >> 4) * 4 + r;
                    float v = fmaxf(acc[it][nt][r] + bb, 0.f);
                    int a = i * 256 + 2 * n;
                    *(f16*)(hsl + (a ^ ((i & 7) << 4))) = (f16)v;
                }
            }
    }
    ISSUEW(2, wC);
    WAITBAR(8);                                  // drains W1; W2 in flight

    ZACC();
    GEMMCORE(hsl, wB);                           // q = tanh(hs@Wq+bq)
    {
        #pragma unroll
        for (int it = 0; it < 2; it++)
            #pragma unroll
            for (int nt = 0; nt < 2; nt++) {
                int n = wv * 32 + nt * 16 + (l & 15);
                float bb = bq[n];
                #pragma unroll
                for (int r = 0; r < 4; r++) {
                    int i = it * 16 + (l >> 4) * 4 + r;
                    q16[(size_t)(r0 + i) * 128 + n] =
                            (f16)fast_tanh(acc[it][nt][r] + bb);
                }
            }
    }
    ISSUEW(3, wA);                               // Wv (W0 buffer free)
    WAITBAR(8);                                  // drains W2 + q stores; W3 in flight

    ZACC();
    GEMMCORE(hsl, wC);                           // k = tanh(hs@Wk+bk) -> ts
    f16* ts = (f16*)xs;
    {
        #pragma unroll
        for (int it = 0; it < 2; it++)
            #pragma unroll
            for (int nt = 0; nt < 2; nt++) {
                int n = wv * 32 + nt * 16 + (l & 15);
                float bb = bk[n];
                #pragma unroll
                for (int r = 0; r < 4; r++) {
                    int i = it * 16 + (l >> 4) * 4 + r;
                    ts[i * 128 + n] = (f16)fast_tanh(acc[it][nt][r] + bb);
                }
            }
    }
    WAITBAR(0);                                  // W3 landed; ts visible

    {   // kimg writes from ts (16KB chunks: 64 rows x 256B)
        #pragma unroll
        for (int half = 0; half < 2; half++) {
            int row = (t >> 4) + half * 16;
            int seg = t & 15;
            int jg = r0 + row;
            int chunk = ((jg >> 10) << 4) + ((jg & 1023) >> 6);
            int jp = jg & 63;
            char* dst = kimg + (size_t)chunk * 16384 + jp * 256
                      + ((seg * 16) ^ ((jp & 7) << 4));
            *(f16x8*)dst = *(const f16x8*)&ts[row * 128 + seg * 8];
        }
    }
    ZACC();
    GEMMCORE(hsl, wA);                           // v = tanh(hs@Wv+bv)
    {
        #pragma unroll
        for (int it = 0; it < 2; it++)
            #pragma unroll
            for (int nt = 0; nt < 2; nt++) {
                int d = wv * 32 + nt * 16 + (l & 15);
                float bb = bv[d];
                f16x4 h;
                #pragma unroll
                for (int r = 0; r < 4; r++)
                    h[r] = (f16)fast_tanh(acc[it][nt][r] + bb);
                int jb = r0 + it * 16 + ((l >> 4) << 2);
                int chunk = ((jb >> 10) << 4) + ((jb & 1023) >> 6);
                char* dst = vimg + (size_t)chunk * 16384 + d * 128
                          + ((2 * (jb & 63)) ^ ((d & 7) << 4));
                *(f16x4*)dst = h;
            }
    }
}

// ---------------------------------------------------------------------------
// attn_all: block = (b = blk&7 XCD-pinned, 32 Q rows), 512 thr / 8 waves.
// Unified chunk stream (18 K'+pek, 18 V'+pev); depth-3 counted vmcnt(4).
// ---------------------------------------------------------------------------
#define ISSUE16(src, bi) do { const char* _g = (src) + t * 16; \
    char* _d = BUF + (size_t)(bi) * 16384 + t * 16; \
    GLDS(_g, _d); \
    GLDS(_g + 8192, _d + 8192); \
} while (0)

__global__ __launch_bounds__(512) void attn_all(
        const f16* __restrict__ q16, const char* __restrict__ kimg,
        const char* __restrict__ pekimg, const char* __restrict__ vimg,
        const char* __restrict__ pevimg, const float* __restrict__ PEK,
        const float* __restrict__ PEV, const char* __restrict__ w1img,
        const float* __restrict__ b1, float* __restrict__ out) {
    extern __shared__ __align__(16) char sm7[];
    f16*   S   = (f16*)sm7;                              // 74240 B
    char*  BUF = sm7 + 74240;                            // 4 x 16384
    f16*   QB  = (f16*)(sm7 + 139776);                   // 8448 B
    float* LR  = (float*)(sm7 + 148224);                 // 128 B

    const int t = threadIdx.x, wv = t >> 6, l = t & 63;
    const int lr = l & 15, lg = l >> 4;
    const int b = blockIdx.x & 7;
    const int i0 = (blockIdx.x >> 3) << 5;
    const int it16 = (wv & 1) << 4;
    const int jsub = wv >> 1;

    // ---- register preloads (ALL global reads happen before chunk issues) ----
    f16x8 qf[4];
    {
        const f16* qb = q16 + (size_t)(b * TT + i0 + it16 + lr) * 128 + lg * 8;
        #pragma unroll
        for (int c = 0; c < 4; c++) qf[c] = *(const f16x8*)(qb + c * 32);
    }
    const int row2 = t >> 4, l16 = t & 15;
    f16x8 qpv = *(const f16x8*)(q16 + (size_t)(b * TT + i0 + row2) * 128 + l16 * 8);
    f32x4 pkv0 = *(const f32x4*)(PEK + 128 * 128 + l16 * 8);
    f32x4 pkv1 = *(const f32x4*)(PEK + 128 * 128 + l16 * 8 + 4);
    f32x4 pvr4 = *(const f32x4*)(PEV + 128 * 128 + wv * 16 + lg * 4);
    const float bb1 = b1[wv * 16 + lr];

    const char* kbase = kimg + (size_t)b * 16 * 16384;
    const char* vbase = vimg + (size_t)b * 16 * 16384;

    // prologue: chunks 0,1,2
    ISSUE16(kbase, 0);
    ISSUE16(kbase + 16384, 1);
    ISSUE16(kbase + 2 * 16384, 2);

    // ---------------- Phase 1: extended QK -> S ----------------
    for (int ch = 0; ch < 18; ch++) {
        asm volatile("s_waitcnt vmcnt(4)" ::: "memory");
        __builtin_amdgcn_s_barrier();
        __builtin_amdgcn_sched_barrier(0);
        {
            int ci = ch + 3;                       // 3..20 (>=18 -> V prefetch)
            const char* src = ci < 16 ? kbase + (size_t)ci * 16384
                            : (ci < 18 ? pekimg + (size_t)(ci - 16) * 16384
                                       : vbase + (size_t)(ci - 18) * 16384);
            ISSUE16(src, ci & 3);
        }
        const char* kb = BUF + (size_t)(ch & 3) * 16384;
        const int jp = jsub * 16 + lr;
        f32x4 acc = {0.f, 0.f, 0.f, 0.f};
        #pragma unroll
        for (int c = 0; c < 4; c++) {
            f16x8 kf = *(const f16x8*)(kb + jp * 256
                        + ((c * 64 + lg * 16) ^ ((jp & 7) << 4)));
            acc = __builtin_amdgcn_mfma_f32_16x16x32_f16(kf, qf[c], acc, 0, 0, 0);
        }
        f16x4 h = {(f16)acc[0], (f16)acc[1], (f16)acc[2], (f16)acc[3]};
        *(f16x4*)&S[(it16 + lr) * SJH + ch * 64 + jsub * 16 + lg * 4] = h;
    }
    asm volatile("s_waitcnt lgkmcnt(0)" ::: "memory");
    __builtin_amdgcn_s_barrier();
    __builtin_amdgcn_sched_barrier(0);

    // ---------------- Phase 2: softmax + buckets (row = t>>4) ----------------
    {
        const int ig = i0 + row2;
        f16* srow = S + row2 * SJH;
        f16* qrow = QB + row2 * 132;

        float qp;   // qpe[row][128] = Q[row] . pe_key[128]  (registers only)
        {
            float s = 0.f;
            #pragma unroll
            for (int e = 0; e < 4; e++) s += (float)qpv[e] * pkv0[e];
            #pragma unroll
            for (int e = 0; e < 4; e++) s += (float)qpv[e + 4] * pkv1[e];
            #pragma unroll
            for (int off = 8; off; off >>= 1) s += __shfl_xor(s, off, 64);
            qp = s;
        }
        for (int mm = l16; mm < 128; mm += 16) {   // qpe S->QB, zero buckets
            qrow[mm] = srow[1024 + mm];
            srow[1024 + mm] = (f16)0.f;
        }
        if (l16 == 0) qrow[128] = (f16)qp;
        const float qlo = (float)qrow[0], qhi = qp;

        float lmax = -3.0e38f;
        #pragma unroll
        for (int kk = 0; kk < 8; kk++) {
            int j0 = kk * 128 + l16 * 8;
            f16x8 sv = *(const f16x8*)(srow + j0);
            #pragma unroll
            for (int e = 0; e < 8; e++) {
                int idd = 64 + j0 + e - ig;
                float qv = (idd <= 0) ? qlo : (idd >= 128 ? qhi : (float)qrow[idd]);
                lmax = fmaxf(lmax, (float)sv[e] + qv);
            }
        }
        #pragma unroll
        for (int off = 8; off; off >>= 1) lmax = fmaxf(lmax, __shfl_xor(lmax, off, 64));

        float lsum = 0.f, s0 = 0.f, s1 = 0.f;
        #pragma unroll
        for (int kk = 0; kk < 8; kk++) {
            int j0 = kk * 128 + l16 * 8;
            f16x8 sv = *(const f16x8*)(srow + j0);
            f16x8 pv;
            #pragma unroll
            for (int e = 0; e < 8; e++) {
                int idd = 64 + j0 + e - ig;
                float qv = (idd <= 0) ? qlo : (idd >= 128 ? qhi : (float)qrow[idd]);
                float p = __expf((float)sv[e] + qv - lmax);
                pv[e] = (f16)p;
                lsum += p;
                if (idd <= 0)        s0 += p;
                else if (idd >= 128) s1 += p;
                else                 srow[1024 + idd] = (f16)p;   // band bucket
            }
            *(f16x8*)(srow + j0) = pv;          // unnormalized P
        }
        #pragma unroll
        for (int off = 8; off; off >>= 1) {
            lsum += __shfl_xor(lsum, off, 64);
            s0   += __shfl_xor(s0,   off, 64);
            s1   += __shfl_xor(s1,   off, 64);
        }
        if (l16 == 0) {
            srow[1024] = (f16)s0;
            srow[1152] = (f16)s1;
            LR[row2] = lsum;
        }
    }
    asm volatile("s_waitcnt lgkmcnt(0)" ::: "memory");
    __builtin_amdgcn_s_barrier();
    __builtin_amdgcn_sched_barrier(0);

    // ---------------- Phase 3: C^T = V'^T . P'^T ----------------
    f32x4 cacc[2] = {};
    for (int ch = 0; ch < 18; ch++) {
        if (ch <= 15)      asm volatile("s_waitcnt vmcnt(4)" ::: "memory");
        else if (ch == 16) asm volatile("s_waitcnt vmcnt(2)" ::: "memory");
        else               asm volatile("s_waitcnt vmcnt(0)" ::: "memory");
        __builtin_amdgcn_s_barrier();
        __builtin_amdgcn_sched_barrier(0);
        if (ch < 15) {
            int ci = ch + 3;                      // local 3..17
            const char* src = ci < 16 ? vbase + (size_t)ci * 16384
                                      : pevimg + (size_t)(ci - 16) * 16384;
            ISSUE16(src, (ci + 2) & 3);
        } else if (ch == 17) {
            // prefetch W1^T image into freed buffers 0..1 (32KB linear)
            const char* _g = w1img + t * 16;
            char* _d = BUF + t * 16;
            #pragma unroll
            for (int _i = 0; _i < 4; _i++)
                GLDS(_g + _i * 8192, _d + _i * 8192);
        }
        const char* vb = BUF + (size_t)((ch + 2) & 3) * 16384;
        const int dp = wv * 16 + lr;
        #pragma unroll
        for (int c2 = 0; c2 < 2; c2++) {
            f16x8 vf = *(const f16x8*)(vb + dp * 128
                        + ((c2 * 64 + lg * 16) ^ ((dp & 7) << 4)));
            #pragma unroll
            for (int i2 = 0; i2 < 2; i2++) {
                f16x8 pf = *(const f16x8*)&S[(i2 * 16 + lr) * SJH
                            + ch * 64 + c2 * 32 + lg * 8];
                cacc[i2] = __builtin_amdgcn_mfma_f32_16x16x32_f16(vf, pf, cacc[i2], 0, 0, 0);
            }
        }
    }

    // ---- epilogue: + w[128]*pe_value[128], normalize -> c-tile in LDS ----
    float w128[2], rden[2];
    #pragma unroll
    for (int i2 = 0; i2 < 2; i2++) {
        int irow = i2 * 16 + lr;
        w128[i2] = (float)S[irow * SJH + 1152];
        rden[i2] = 1.f / LR[irow];
    }
    asm volatile("s_waitcnt lgkmcnt(0)" ::: "memory");
    __builtin_amdgcn_s_barrier();                        // all S reads done
    __builtin_amdgcn_sched_barrier(0);
    char* cl = (char*)S;                                 // c-tile [i][d] swizzled
    {
        #pragma unroll
        for (int i2 = 0; i2 < 2; i2++) {
            int i = i2 * 16 + lr;
            #pragma unroll
            for (int r = 0; r < 4; r++) {
                int d = wv * 16 + lg * 4 + r;
                float cv = (cacc[i2][r] + w128[i2] * pvr4[r]) * rden[i2];
                int a = i * 256 + 2 * d;
                *(f16*)(cl + (a ^ ((i & 7) << 4))) = (f16)cv;
            }
        }
    }
    asm volatile("s_waitcnt vmcnt(0) lgkmcnt(0)" ::: "memory");
    __builtin_amdgcn_s_barrier();                        // W1 landed, cl visible
    __builtin_amdgcn_sched_barrier(0);

    // ---- tail GEMM: out = relu(c @ W1 + b1), fp32 ----
    const char* wl4 = BUF;
    f32x4 oacc[2] = {};
    #pragma unroll
    for (int c = 0; c < 4; c++) {
        f16x8 af[2], bf;
        #pragma unroll
        for (int i2 = 0; i2 < 2; i2++) {
            int row = i2 * 16 + lr;
            int a = (row << 8) + (c << 6) + (lg << 4);
            af[i2] = *(const f16x8*)(cl + (a ^ ((row & 7) << 4)));
        }
        {
            int n = wv * 16 + lr;
            int a = (n << 8) + (c << 6) + (lg << 4);
            bf = *(const f16x8*)(wl4 + (a ^ ((n & 7) << 4)));
        }
        #pragma unroll
        for (int i2 = 0; i2 < 2; i2++)
            oacc[i2] = __builtin_amdgcn_mfma_f32_16x16x32_f16(af[i2], bf, oacc[i2], 0, 0, 0);
    }
    {
        int n = wv * 16 + lr;
        #pragma unroll
        for (int i2 = 0; i2 < 2; i2++) {
            #pragma unroll
            for (int r = 0; r < 4; r++) {
                int i = i2 * 16 + lg * 4 + r;
                out[(size_t)(b * TT + i0 + i) * DD + n] = fmaxf(oacc[i2][r] + bb1, 0.f);
            }
        }
    }
}

// ---------------------------------------------------------------------------

extern "C" void kernel_launch(void* const* d_in, const int* in_sizes, int n_in,
                              void* d_out, int out_size, void* d_ws, size_t ws_size,
                              hipStream_t stream) {
    const float* x   = (const float*)d_in[0];
    const float* W0  = (const float*)d_in[1];
    const float* b0  = (const float*)d_in[2];
    const float* Wq  = (const float*)d_in[3];
    const float* bq  = (const float*)d_in[4];
    const float* Wk  = (const float*)d_in[5];
    const float* bk  = (const float*)d_in[6];
    const float* Wv  = (const float*)d_in[7];
    const float* bv  = (const float*)d_in[8];
    const float* W1  = (const float*)d_in[9];
    const float* b1  = (const float*)d_in[10];
    const float* pek = (const float*)d_in[11];
    const float* pev = (const float*)d_in[12];
    float* out = (float*)d_out;

    const size_t NTD = (size_t)NB * TT * DD;   // 1,048,576 elements
    f16* q16 = (f16*)d_ws;                     // 2 MB
    char* wimg   = (char*)(q16 + NTD);         // 5 x 32KB
    char* kimg   = wimg + 5 * 32768;           // 128 x 16KB = 2 MB
    char* vimg   = kimg + (size_t)128 * 16384; // 2 MB
    char* pekimg = vimg + (size_t)128 * 16384; // 32 KB
    char* pevimg = pekimg + 32768;             // 32 KB

    const int SMEM_QKV  = 114688;
    const int SMEM_ATTN = 148352;
    hipFuncSetAttribute(reinterpret_cast<const void*>(fused_qkv),
                        hipFuncAttributeMaxDynamicSharedMemorySize, SMEM_QKV);
    hipFuncSetAttribute(reinterpret_cast<const void*>(attn_all),
                        hipFuncAttributeMaxDynamicSharedMemorySize, SMEM_ATTN);

    hipLaunchKernelGGL(prep_w, dim3(5), dim3(256), 0, stream,
                       W0, Wq, Wk, Wv, W1, wimg);
    hipLaunchKernelGGL(fused_qkv, dim3(258), dim3(256), SMEM_QKV, stream,
                       x, wimg, b0, bq, bk, bv, pek, pev,
                       q16, kimg, vimg, pekimg, pevimg);
    hipLaunchKernelGGL(attn_all, dim3(256), dim3(512), SMEM_ATTN, stream,
                       q16, kimg, pekimg, vimg, pevimg, pek, pev,
                       wimg + 4 * 32768, b1, out);
}